// Round 15
// baseline (324.182 us; speedup 1.0000x reference)
//
#include <hip/hip_runtime.h>
#include <math.h>

#define NB 512
#define NPQ 128
#define NY 1024
#define NO 256
#define NTOT 1408   // NPQ+NY+NO

typedef __attribute__((ext_vector_type(8))) short bf16x8;
typedef __attribute__((ext_vector_type(4))) float f32x4;

__device__ __forceinline__ unsigned short f2bf(float f) {
    unsigned int u = __float_as_uint(f);
    u += 0x7fffu + ((u >> 16) & 1u);   // RTNE
    return (unsigned short)(u >> 16);
}
__device__ __forceinline__ float bf2f(short s) {
    return __uint_as_float(((unsigned int)(unsigned short)s) << 16);
}

union U8  { bf16x8 v; unsigned long long u[2]; };
union U16 { bf16x8 v; uint4 u; };

// ============================================================================
// Kernel 0a: parallel weight folding, stage A (byte-identical to R13/R14).
// ============================================================================
__global__ __launch_bounds__(256) void k_prepA(
    const float* __restrict__ emb,  const float* __restrict__ e0b2,
    const float* __restrict__ e0w2, const float* __restrict__ wq,
    const float* __restrict__ bq,   const float* __restrict__ wp,
    const float* __restrict__ bp,   const float* __restrict__ bk,
    const float* __restrict__ wvv,  const float* __restrict__ bv,
    const float* __restrict__ wo,   const float* __restrict__ bo,
    const float* __restrict__ e1b2, const float* __restrict__ e1w2,
    const float* __restrict__ e2b2, const float* __restrict__ e2w2,
    const float* __restrict__ nw1,  const float* __restrict__ nw2,
    float* __restrict__ W2qG, float* __restrict__ WvoG,
    float* __restrict__ scqG, float* __restrict__ b0g0,
    float* __restrict__ bvo,  float* __restrict__ BEP,
    unsigned short* __restrict__ W2P, unsigned short* __restrict__ WHP)
{
    const int tid = threadIdx.x, blk = blockIdx.x;

    if (blk < 16) {
        const int idx = blk*256 + tid;
        const int h = idx >> 6, j = idx & 63;
        float s0 = 0.f, s1 = 0.f, s2 = 0.f, s3 = 0.f;
        #pragma unroll 4
        for (int e = 0; e < 64; e += 4) {
            s0 = fmaf(e0w2[h*64+e],   wq[(e  )*64+j], s0);
            s1 = fmaf(e0w2[h*64+e+1], wq[(e+1)*64+j], s1);
            s2 = fmaf(e0w2[h*64+e+2], wq[(e+2)*64+j], s2);
            s3 = fmaf(e0w2[h*64+e+3], wq[(e+3)*64+j], s3);
        }
        W2qG[idx] = (s0 + s1) + (s2 + s3);
    } else if (blk < 32) {
        const int idx = (blk-16)*256 + tid;
        const int e = idx >> 6, o = idx & 63;
        float s0 = 0.f, s1 = 0.f, s2 = 0.f, s3 = 0.f;
        #pragma unroll 4
        for (int d = 0; d < 64; d += 4) {
            s0 = fmaf(wvv[e*64+d],   wo[(d  )*64+o], s0);
            s1 = fmaf(wvv[e*64+d+1], wo[(d+1)*64+o], s1);
            s2 = fmaf(wvv[e*64+d+2], wo[(d+2)*64+o], s2);
            s3 = fmaf(wvv[e*64+d+3], wo[(d+3)*64+o], s3);
        }
        WvoG[idx] = (s0 + s1) + (s2 + s3);
    } else if (blk < 38) {
        const int idx = (blk-32)*256 + tid;
        if (idx < 1536) {
            const int t = idx >> 9, rem = idx & 511;
            const int mt = rem >> 7, rem2 = rem & 127;
            const int kh = rem2 >> 6, lane = rem2 & 63;
            const int quad = lane >> 4, lq = lane & 15;
            const float* w2 = (t == 0) ? e0w2 : ((t == 1) ? e1w2 : e2w2);
            unsigned short v[8];
            #pragma unroll
            for (int j = 0; j < 8; ++j)
                v[j] = f2bf(w2[(kh*32 + quad*8 + j)*64 + mt*16 + lq]);
            *(uint4*)&W2P[(size_t)idx*8] = make_uint4(
                (unsigned int)v[0] | ((unsigned int)v[1] << 16),
                (unsigned int)v[2] | ((unsigned int)v[3] << 16),
                (unsigned int)v[4] | ((unsigned int)v[5] << 16),
                (unsigned int)v[6] | ((unsigned int)v[7] << 16));
        }
    } else if (blk < 42) {
        const int idx = 512 + (blk-38)*256 + tid;
        const int l = idx >> 9, rem = idx & 511;
        const int mt = rem >> 7, rem2 = rem & 127;
        const int kh = rem2 >> 6, lane = rem2 & 63;
        const int quad = lane >> 4, lq = lane & 15;
        const float* W = (l == 1) ? nw1 : nw2;
        unsigned short v[8];
        #pragma unroll
        for (int j = 0; j < 8; ++j)
            v[j] = f2bf(W[(kh*32 + quad*8 + j)*64 + mt*16 + lq]);
        *(uint4*)&WHP[(size_t)idx*8] = make_uint4(
            (unsigned int)v[0] | ((unsigned int)v[1] << 16),
            (unsigned int)v[2] | ((unsigned int)v[3] << 16),
            (unsigned int)v[4] | ((unsigned int)v[5] << 16),
            (unsigned int)v[6] | ((unsigned int)v[7] << 16));
    } else {
        __shared__ float scq[64];
        if (tid < 64) {
            const int j = tid;
            float s = bq[j];
            for (int e = 0; e < 64; ++e) s += (e0b2[e] + emb[e]) * wq[e*64+j];
            scq[j] = s;
            scqG[j] = s;
        }
        if (tid >= 64 && tid < 128) {
            const int o = tid - 64;
            float s = bo[o];
            for (int d = 0; d < 64; ++d) s += bv[d] * wo[d*64+o];
            bvo[o] = s;
        }
        {
            const int i = tid - 64;
            if (i >= 64 && i < 256) {
                const int idx = i - 64;   // 0..191
                const int t = idx >> 6, d = idx & 63;
                const float* b2 = (t == 0) ? e0b2 : ((t == 1) ? e1b2 : e2b2);
                BEP[idx] = b2[d] + emb[t*64 + d];
            }
        }
        __syncthreads();
        if (tid == 0) {
            float s0 = 0.f, s1 = 0.f, s2 = 0.f;
            for (int j = 0; j < 64; ++j) {
                s0 += scq[j] * wp[j];
                s1 += scq[j] * wp[64+j];
                s2 += scq[j] * (bp[j] + bk[j]);
            }
            b0g0[0] = s0; b0g0[1] = s1; b0g0[2] = s2;
        }
    }
}

// ============================================================================
// Kernel 0b: stage B (byte-identical to R13/R14).
// ============================================================================
__global__ __launch_bounds__(256) void k_prepB(
    const float* __restrict__ W2qG, const float* __restrict__ WvoG,
    const float* __restrict__ scqG,
    const float* __restrict__ wk, const float* __restrict__ wp,
    const float* __restrict__ bp, const float* __restrict__ bk,
    unsigned short* __restrict__ AqkP, unsigned short* __restrict__ P3P,
    float* __restrict__ a0, unsigned short* __restrict__ WHP)
{
    const int tid = threadIdx.x, blk = blockIdx.x;

    if (blk < 2) {
        const int idx = blk*256 + tid;
        const int fi = idx >> 6, lane = idx & 63;
        const int mt = fi >> 1, kh = fi & 1;
        const int quad = lane >> 4, lq = lane & 15;
        const int d = mt*16 + lq;
        unsigned short v[8];
        #pragma unroll
        for (int jj = 0; jj < 8; ++jj) {
            const int h = kh*32 + quad*8 + jj;
            float s0 = 0.f, s1 = 0.f, s2 = 0.f, s3 = 0.f;
            #pragma unroll 4
            for (int j = 0; j < 64; j += 4) {
                const float4 a = *(const float4*)&W2qG[h*64 + j];
                const float4 b = *(const float4*)&wk[d*64 + j];
                s0 = fmaf(a.x, b.x, s0); s1 = fmaf(a.y, b.y, s1);
                s2 = fmaf(a.z, b.z, s2); s3 = fmaf(a.w, b.w, s3);
            }
            v[jj] = f2bf((s0 + s1) + (s2 + s3));
        }
        *(uint4*)&AqkP[(size_t)idx*8] = make_uint4(
            (unsigned int)v[0] | ((unsigned int)v[1] << 16),
            (unsigned int)v[2] | ((unsigned int)v[3] << 16),
            (unsigned int)v[4] | ((unsigned int)v[5] << 16),
            (unsigned int)v[6] | ((unsigned int)v[7] << 16));
    } else if (blk == 2) {
        if (tid < 128) {
            const int idx = tid;
            const int kh = idx >> 6, lane = idx & 63;
            const int quad = lane >> 4, lq = lane & 15;
            unsigned short v[8];
            #pragma unroll
            for (int jj = 0; jj < 8; ++jj) {
                const int h = kh*32 + quad*8 + jj;
                float val = 0.f;
                if (lq == 0 || lq == 1) {
                    float s0 = 0.f, s1 = 0.f;
                    #pragma unroll 8
                    for (int j = 0; j < 64; j += 2) {
                        s0 = fmaf(W2qG[h*64+j],   wp[lq*64+j],   s0);
                        s1 = fmaf(W2qG[h*64+j+1], wp[lq*64+j+1], s1);
                    }
                    val = s0 + s1;
                } else if (lq == 2) {
                    float s0 = 0.f, s1 = 0.f;
                    #pragma unroll 8
                    for (int j = 0; j < 64; j += 2) {
                        s0 = fmaf(W2qG[h*64+j],   bp[j]   + bk[j],   s0);
                        s1 = fmaf(W2qG[h*64+j+1], bp[j+1] + bk[j+1], s1);
                    }
                    val = s0 + s1;
                }
                v[jj] = f2bf(val);
            }
            *(uint4*)&P3P[(size_t)idx*8] = make_uint4(
                (unsigned int)v[0] | ((unsigned int)v[1] << 16),
                (unsigned int)v[2] | ((unsigned int)v[3] << 16),
                (unsigned int)v[4] | ((unsigned int)v[5] << 16),
                (unsigned int)v[6] | ((unsigned int)v[7] << 16));
        } else if (tid < 192) {
            const int d = tid - 128;
            float s0 = 0.f, s1 = 0.f, s2 = 0.f, s3 = 0.f;
            #pragma unroll 4
            for (int j = 0; j < 64; j += 4) {
                const float4 a = *(const float4*)&scqG[j];
                const float4 b = *(const float4*)&wk[d*64 + j];
                s0 = fmaf(a.x, b.x, s0); s1 = fmaf(a.y, b.y, s1);
                s2 = fmaf(a.z, b.z, s2); s3 = fmaf(a.w, b.w, s3);
            }
            a0[d] = (s0 + s1) + (s2 + s3);
        }
    } else {
        #pragma unroll
        for (int pass = 0; pass < 2; ++pass) {
            const int idx = pass*256 + tid;           // 0..511
            const int mt = idx >> 7, rem2 = idx & 127;
            const int kh = rem2 >> 6, lane = rem2 & 63;
            const int quad = lane >> 4, lq = lane & 15;
            unsigned short v[8];
            #pragma unroll
            for (int j = 0; j < 8; ++j)
                v[j] = f2bf(WvoG[(kh*32 + quad*8 + j)*64 + mt*16 + lq]);
            *(uint4*)&WHP[(size_t)idx*8] = make_uint4(
                (unsigned int)v[0] | ((unsigned int)v[1] << 16),
                (unsigned int)v[2] | ((unsigned int)v[3] << 16),
                (unsigned int)v[4] | ((unsigned int)v[5] << 16),
                (unsigned int)v[6] | ((unsigned int)v[7] << 16));
        }
    }
}

// ============================================================================
// Kernel 1: MERGED encoders + queries (byte-identical to R13/R14 — verified).
// ============================================================================
__global__ __launch_bounds__(256) void k_encq(
    const float* __restrict__ pred, const float* __restrict__ prey,
    const float* __restrict__ obst,
    const unsigned short* __restrict__ W2P, const float* __restrict__ BEP,
    const float* __restrict__ e0w1, const float* __restrict__ e0b1,
    const float* __restrict__ e1w1, const float* __restrict__ e1b1,
    const float* __restrict__ e2w1, const float* __restrict__ e2b1,
    const unsigned short* __restrict__ AqkP, const float* __restrict__ a0,
    const unsigned short* __restrict__ P3P,  const float* __restrict__ b0g0,
    unsigned short* __restrict__ X, float* __restrict__ POS,
    float* __restrict__ QT, float* __restrict__ QP, float* __restrict__ QC)
{
    const int tid = threadIdx.x, lane = tid & 63, w = tid >> 6;
    const int lq = lane & 15, quad = lane >> 4;
    __shared__ __align__(16) short sH[4][32][68];

    if (blockIdx.x < 1408) {
        const int blk = blockIdx.x;
        int type, lrow0, cin, lsh, nmask, nbase;
        const float *st, *w1, *b1;
        if (blk < 128)       { type=0; lrow0=blk*512;         st=pred; w1=e0w1; b1=e0b1; cin=2; lsh=7;  nmask=NPQ-1; nbase=0; }
        else if (blk < 1152) { type=1; lrow0=(blk-128)*512;   st=prey; w1=e1w1; b1=e1b1; cin=2; lsh=10; nmask=NY-1;  nbase=NPQ; }
        else                 { type=2; lrow0=(blk-1152)*512;  st=obst; w1=e2w1; b1=e2b1; cin=3; lsh=8;  nmask=NO-1;  nbase=NPQ+NY; }

        bf16x8 wfrag[4][2];
        #pragma unroll
        for (int mt = 0; mt < 4; ++mt)
            #pragma unroll
            for (int kh = 0; kh < 2; ++kh)
                wfrag[mt][kh] = *(const bf16x8*)&W2P[(size_t)(((type*4 + mt)*2 + kh)*64 + lane)*8];

        float4 be[4];
        #pragma unroll
        for (int mt = 0; mt < 4; ++mt)
            be[mt] = *(const float4*)&BEP[type*64 + mt*16 + quad*4];

        float b1v[2][8], w0v[2][8], w1v[2][8], w2v[2][8];
        #pragma unroll
        for (int kh = 0; kh < 2; ++kh) {
            const int k0 = kh*32 + quad*8;
            *(float4*)&b1v[kh][0] = *(const float4*)&b1[k0];
            *(float4*)&b1v[kh][4] = *(const float4*)&b1[k0+4];
            *(float4*)&w0v[kh][0] = *(const float4*)&w1[k0];
            *(float4*)&w0v[kh][4] = *(const float4*)&w1[k0+4];
            *(float4*)&w1v[kh][0] = *(const float4*)&w1[64+k0];
            *(float4*)&w1v[kh][4] = *(const float4*)&w1[64+k0+4];
            if (cin == 3) {
                *(float4*)&w2v[kh][0] = *(const float4*)&w1[128+k0];
                *(float4*)&w2v[kh][4] = *(const float4*)&w1[128+k0+4];
            }
        }

        #pragma unroll
        for (int k = 0; k < 4; ++k) {
            const int i = tid*4 + k;
            const int r = i >> 1, c = i & 1;
            const int lr = lrow0 + r;
            const int pb = lr >> lsh, n = nbase + (lr & nmask);
            POS[((size_t)pb*NTOT + n)*2 + c] = st[(size_t)lr*cin + c];
        }

        for (int rt = 0; rt < 8; ++rt) {
            const int lr = lrow0 + w*128 + rt*16 + lq;
            float s0, s1, s2 = 0.f;
            if (cin == 2) {
                const float2 sv = *(const float2*)&st[(size_t)lr*2];
                s0 = sv.x; s1 = sv.y;
            } else {
                const float2 sv = *(const float2*)&st[(size_t)lr*3];
                s0 = sv.x; s1 = sv.y; s2 = st[(size_t)lr*3 + 2];
            }
            bf16x8 hb[2];
            #pragma unroll
            for (int kh = 0; kh < 2; ++kh)
                #pragma unroll
                for (int j = 0; j < 8; ++j) {
                    float a = b1v[kh][j] + s0*w0v[kh][j] + s1*w1v[kh][j];
                    if (cin == 3) a += s2*w2v[kh][j];
                    hb[kh][j] = (short)f2bf(fmaxf(a, 0.f));
                }

            f32x4 acc[4];
            #pragma unroll
            for (int mt = 0; mt < 4; ++mt) acc[mt] = (f32x4){0.f,0.f,0.f,0.f};
            #pragma unroll
            for (int mt = 0; mt < 4; ++mt) {
                acc[mt] = __builtin_amdgcn_mfma_f32_16x16x32_bf16(wfrag[mt][0], hb[0], acc[mt], 0, 0, 0);
                acc[mt] = __builtin_amdgcn_mfma_f32_16x16x32_bf16(wfrag[mt][1], hb[1], acc[mt], 0, 0, 0);
            }

            const int bb = lr >> lsh, n = nbase + (lr & nmask);
            unsigned short* xbase = X + ((size_t)bb*NTOT + n)*64;
            #pragma unroll
            for (int mt = 0; mt < 4; ++mt) {
                const unsigned int u0 = (unsigned int)f2bf(acc[mt][0] + be[mt].x)
                                      | ((unsigned int)f2bf(acc[mt][1] + be[mt].y) << 16);
                const unsigned int u1 = (unsigned int)f2bf(acc[mt][2] + be[mt].z)
                                      | ((unsigned int)f2bf(acc[mt][3] + be[mt].w) << 16);
                *(uint2*)(xbase + mt*16 + quad*4) = make_uint2(u0, u1);
            }
        }
    } else {
        const int b = blockIdx.x - 1408;
        const float w1r0 = e0w1[lane], w1r1 = e0w1[64+lane], b1r = e0b1[lane];
        {
            const float* sp = pred + ((size_t)b*NPQ + w*32)*2;
            #pragma unroll
            for (int r = 0; r < 32; ++r) {
                const float a = b1r + sp[2*r]*w1r0 + sp[2*r+1]*w1r1;
                sH[w][r][lane] = (short)f2bf(fmaxf(a, 0.f));
            }
        }

        bf16x8 wfrag[4][2], a3[2];
        #pragma unroll
        for (int mt = 0; mt < 4; ++mt)
            #pragma unroll
            for (int kh = 0; kh < 2; ++kh)
                wfrag[mt][kh] = *(const bf16x8*)&AqkP[(size_t)((mt*2 + kh)*64 + lane)*8];
        #pragma unroll
        for (int kh = 0; kh < 2; ++kh)
            a3[kh] = *(const bf16x8*)&P3P[(size_t)(kh*64 + lane)*8];

        float4 a0r[4];
        #pragma unroll
        for (int mt = 0; mt < 4; ++mt) a0r[mt] = *(const float4*)&a0[mt*16 + quad*4];
        const float c0 = b0g0[0], c1 = b0g0[1], c2 = b0g0[2];

        __syncthreads();

        for (int bt = 0; bt < 2; ++bt) {
            U8 hb0, hb1;
            const short* hp = &sH[w][bt*16 + lq][0];
            hb0.u[0] = *(const unsigned long long*)(hp + quad*8);
            hb0.u[1] = *(const unsigned long long*)(hp + quad*8 + 4);
            hb1.u[0] = *(const unsigned long long*)(hp + 32 + quad*8);
            hb1.u[1] = *(const unsigned long long*)(hp + 32 + quad*8 + 4);

            f32x4 acc[4], acc3;
            #pragma unroll
            for (int mt = 0; mt < 4; ++mt) acc[mt] = (f32x4){0.f,0.f,0.f,0.f};
            acc3 = (f32x4){0.f,0.f,0.f,0.f};
            #pragma unroll
            for (int mt = 0; mt < 4; ++mt) {
                acc[mt] = __builtin_amdgcn_mfma_f32_16x16x32_bf16(wfrag[mt][0], hb0.v, acc[mt], 0, 0, 0);
                acc[mt] = __builtin_amdgcn_mfma_f32_16x16x32_bf16(wfrag[mt][1], hb1.v, acc[mt], 0, 0, 0);
            }
            acc3 = __builtin_amdgcn_mfma_f32_16x16x32_bf16(a3[0], hb0.v, acc3, 0, 0, 0);
            acc3 = __builtin_amdgcn_mfma_f32_16x16x32_bf16(a3[1], hb1.v, acc3, 0, 0, 0);

            const int row = b*NPQ + w*32 + bt*16 + lq;
            #pragma unroll
            for (int mt = 0; mt < 4; ++mt) {
                *(float4*)&QT[(size_t)row*64 + mt*16 + quad*4] = make_float4(
                    acc[mt][0] + a0r[mt].x, acc[mt][1] + a0r[mt].y,
                    acc[mt][2] + a0r[mt].z, acc[mt][3] + a0r[mt].w);
            }
            if (quad == 0) {
                const float qp0 = acc3[0] + c0, qp1 = acc3[1] + c1, qs = acc3[2] + c2;
                const float p0 = pred[(size_t)row*2], p1 = pred[(size_t)row*2 + 1];
                QP[(size_t)row*2]     = qp0;
                QP[(size_t)row*2 + 1] = qp1;
                QC[row] = qp0*p0 + qp1*p1 + qs;
            }
        }
    }
}

// ============================================================================
// Kernel 3 (R15): flash attention + fused head, Q-SPLIT: 1024 blocks =
// (batch, q-half of 64). Exact partition of R14's arithmetic (each q's score
// row, l-sum order, O accumulation order, and head path are unchanged =>
// bitwise-identical output). Per wave: 1 q m-tile (16 q), S=8 MFMA, PV=8
// MFMA, 16 scores/lane/tile. LDS 43.8 KB -> 3 blocks/CU; grid 1024 gives the
// barrier-chain blocks real overlap. Head runs on the block's own 64 rows
// (head is row-local). Hazard structure identical to R12/R14 (verified).
// ============================================================================
__global__ __launch_bounds__(256, 3) void k_attn(
    const unsigned short* __restrict__ X, const float* __restrict__ POS,
    const float* __restrict__ QT, const float* __restrict__ QP,
    const float* __restrict__ QC,
    const unsigned short* __restrict__ WHP,
    const float* __restrict__ bvo, const float* __restrict__ nb1,
    const float* __restrict__ nb2,
    const float* __restrict__ nw3, const float* __restrict__ nb3,
    float* __restrict__ OUT)
{
    const int tid = threadIdx.x;
    const int b = blockIdx.x >> 1, qh = blockIdx.x & 1;
    const int w = tid >> 6, lane = tid & 63, lq = lane & 15, quad = lane >> 4;
    const int qbase = qh*64 + w*16;   // this wave's 16 q rows (global in batch)

    __shared__ __align__(16) short sXc[2][64][68];   // [buf][d][key] (X^T)
    __shared__ __align__(16) short sP[4][16][68];    // per-wave [q][key]
    __shared__ __align__(16) short sA[64][68];       // head ping
    __shared__ __align__(16) short sB[64][68];       // head pong
    __shared__ float sw3[64];

    bf16x8 aq[2];
    {
        const float* qrow = QT + ((size_t)b*NPQ + qbase + lq)*64;
        #pragma unroll
        for (int kh = 0; kh < 2; ++kh)
            #pragma unroll
            for (int j = 0; j < 8; ++j)
                aq[kh][j] = (short)f2bf(qrow[kh*32 + quad*8 + j]);
    }

    float qcr[4], qp0r[4], qp1r[4], lacc[4];
    f32x4 O[4];
    #pragma unroll
    for (int i = 0; i < 4; ++i) {
        const size_t g = (size_t)b*NPQ + qbase + quad*4 + i;
        qcr[i]  = QC[g];
        qp0r[i] = -QP[2*g];
        qp1r[i] = -QP[2*g+1];
        lacc[i] = 0.f;
        O[i] = (f32x4){0.f, 0.f, 0.f, 0.f};
    }
    const float E = 0.180336884f;   // (1/sqrt(64)) * log2(e)

    const int skey = tid & 63, sd0 = (tid >> 6) * 16;

    for (int kt = 0; kt < 22; ++kt) {
        const int par = kt & 1;

        const unsigned short* gx = X + ((size_t)b*NTOT + kt*64 + skey)*64 + sd0;
        const uint4 t0 = *(const uint4*)(gx);
        const uint4 t1 = *(const uint4*)(gx + 8);

        // ---- PV(kt-1): A = sP (own wave), B = sXc[par^1] ----
        if (kt > 0) {
            const int pb = par ^ 1;
            #pragma unroll
            for (int kc = 0; kc < 2; ++kc) {
                U8 pa;
                const short* pp = &sP[w][lq][kc*32 + quad*8];
                pa.u[0] = *(const unsigned long long*)pp;
                pa.u[1] = *(const unsigned long long*)(pp + 4);
                #pragma unroll
                for (int nt = 0; nt < 4; ++nt) {
                    U8 bv;
                    const short* xp = &sXc[pb][nt*16 + lq][kc*32 + quad*8];
                    bv.u[0] = *(const unsigned long long*)xp;
                    bv.u[1] = *(const unsigned long long*)(xp + 4);
                    O[nt] = __builtin_amdgcn_mfma_f32_16x16x32_bf16(pa.v, bv.v, O[nt], 0, 0, 0);
                }
            }
        }

        __builtin_amdgcn_sched_barrier(0);   // same-wave WAR on sP (R12 pattern)

        // ---- S(kt): B-frags from global X rows; epilogue -> sP ----
        #pragma unroll
        for (int nt = 0; nt < 4; ++nt) {
            U16 bx0, bx1;
            const unsigned short* xrow = X + ((size_t)b*NTOT + kt*64 + nt*16 + lq)*64;
            bx0.u = *(const uint4*)(xrow + quad*8);
            bx1.u = *(const uint4*)(xrow + 32 + quad*8);
            const float pos0 = POS[((size_t)b*NTOT + kt*64 + nt*16 + lq)*2];
            const float pos1 = POS[((size_t)b*NTOT + kt*64 + nt*16 + lq)*2 + 1];
            f32x4 sa = (f32x4){0.f,0.f,0.f,0.f};
            sa = __builtin_amdgcn_mfma_f32_16x16x32_bf16(aq[0], bx0.v, sa, 0, 0, 0);
            sa = __builtin_amdgcn_mfma_f32_16x16x32_bf16(aq[1], bx1.v, sa, 0, 0, 0);
            #pragma unroll
            for (int i = 0; i < 4; ++i) {
                float s = sa[i] + qcr[i];
                s = fmaf(qp0r[i], pos0, s);
                s = fmaf(qp1r[i], pos1, s);
                const float p = exp2f(s * E);
                lacc[i] += p;
                sP[w][quad*4 + i][nt*16 + lq] = (short)f2bf(p);
            }
        }

        // ---- stage X(kt) -> sXc[par] (R9-proven pattern, constant idx) ----
        {
            unsigned short tmp[16];
            *(uint4*)tmp = t0; *(uint4*)(tmp+8) = t1;
            #pragma unroll
            for (int j = 0; j < 16; ++j) sXc[par][sd0+j][skey] = (short)tmp[j];
        }

        __syncthreads();
    }

    // ---- final PV(kt=21): sXc[1], sP written pre-final-barrier ----
    {
        #pragma unroll
        for (int kc = 0; kc < 2; ++kc) {
            U8 pa;
            const short* pp = &sP[w][lq][kc*32 + quad*8];
            pa.u[0] = *(const unsigned long long*)pp;
            pa.u[1] = *(const unsigned long long*)(pp + 4);
            #pragma unroll
            for (int nt = 0; nt < 4; ++nt) {
                U8 bv;
                const short* xp = &sXc[1][nt*16 + lq][kc*32 + quad*8];
                bv.u[0] = *(const unsigned long long*)xp;
                bv.u[1] = *(const unsigned long long*)(xp + 4);
                O[nt] = __builtin_amdgcn_mfma_f32_16x16x32_bf16(pa.v, bv.v, O[nt], 0, 0, 0);
            }
        }
    }

    // ---- attention epilogue -> sA (bf16), same values as R14 ----
    #pragma unroll
    for (int i = 0; i < 4; ++i) {
        #pragma unroll
        for (int off = 1; off < 16; off <<= 1)
            lacc[i] += __shfl_xor(lacc[i], off);
        const float rl = 1.f / lacc[i];
        const int row = w*16 + quad*4 + i;           // local row 0..63
        #pragma unroll
        for (int nt = 0; nt < 4; ++nt)
            sA[row][nt*16 + lq] = (short)f2bf(O[nt][i] * rl);
    }
    if (tid < 64) sw3[tid] = nw3[tid];
    __syncthreads();   // sA complete before head reads (R2 lesson)

    // ---- fused head on this block's 64 rows (verified body, 1 bt pass) ----
    const float* Bs[3] = {bvo, nb1, nb2};
    for (int l = 0; l < 3; ++l) {
        bf16x8 wfrag[4][2];
        #pragma unroll
        for (int mt = 0; mt < 4; ++mt)
            #pragma unroll
            for (int kh = 0; kh < 2; ++kh)
                wfrag[mt][kh] = *(const bf16x8*)&WHP[(size_t)(((l*4 + mt)*2 + kh)*64 + lane)*8];
        const float* Bb = Bs[l];
        float be[4][4];
        #pragma unroll
        for (int mt = 0; mt < 4; ++mt)
            #pragma unroll
            for (int i = 0; i < 4; ++i) be[mt][i] = Bb[mt*16 + quad*4 + i];

        short (*src)[68] = (l & 1) ? sB : sA;
        short (*dst)[68] = (l & 1) ? sA : sB;
        const bool doRelu = (l >= 1);

        {
            U8 hb0, hb1;
            const short* hp = &src[w*16 + lq][0];
            hb0.u[0] = *(const unsigned long long*)(hp + quad*8);
            hb0.u[1] = *(const unsigned long long*)(hp + quad*8 + 4);
            hb1.u[0] = *(const unsigned long long*)(hp + 32 + quad*8);
            hb1.u[1] = *(const unsigned long long*)(hp + 32 + quad*8 + 4);

            f32x4 acc[4];
            #pragma unroll
            for (int mt = 0; mt < 4; ++mt) acc[mt] = (f32x4){0.f,0.f,0.f,0.f};
            #pragma unroll
            for (int mt = 0; mt < 4; ++mt) {
                acc[mt] = __builtin_amdgcn_mfma_f32_16x16x32_bf16(wfrag[mt][0], hb0.v, acc[mt], 0, 0, 0);
                acc[mt] = __builtin_amdgcn_mfma_f32_16x16x32_bf16(wfrag[mt][1], hb1.v, acc[mt], 0, 0, 0);
            }
            const int row = w*16 + lq;
            #pragma unroll
            for (int mt = 0; mt < 4; ++mt) {
                float v0 = acc[mt][0] + be[mt][0];
                float v1 = acc[mt][1] + be[mt][1];
                float v2 = acc[mt][2] + be[mt][2];
                float v3 = acc[mt][3] + be[mt][3];
                if (doRelu) {
                    v0 = fmaxf(v0, 0.f); v1 = fmaxf(v1, 0.f);
                    v2 = fmaxf(v2, 0.f); v3 = fmaxf(v3, 0.f);
                }
                const unsigned int u0 = (unsigned int)f2bf(v0) | ((unsigned int)f2bf(v1) << 16);
                const unsigned int u1 = (unsigned int)f2bf(v2) | ((unsigned int)f2bf(v3) << 16);
                *(uint2*)&dst[row][mt*16 + quad*4] = make_uint2(u0, u1);
            }
        }
        __syncthreads();
    }

    if (tid < 64) {
        const int row = tid;
        float acc = nb3[0];
        #pragma unroll 16
        for (int d = 0; d < 64; ++d) acc += bf2f(sB[row][d]) * sw3[d];
        OUT[(size_t)b*NPQ + qh*64 + row] = tanhf(acc);
    }
}

// ============================================================================
extern "C" void kernel_launch(void* const* d_in, const int* in_sizes, int n_in,
                              void* d_out, int out_size, void* d_ws, size_t ws_size,
                              hipStream_t stream)
{
    const float* pred = (const float*)d_in[0];
    const float* prey = (const float*)d_in[1];
    const float* obst = (const float*)d_in[2];
    const float* emb  = (const float*)d_in[4];
    const float* e0w1 = (const float*)d_in[5];
    const float* e0b1 = (const float*)d_in[6];
    const float* e0w2 = (const float*)d_in[7];
    const float* e0b2 = (const float*)d_in[8];
    const float* e1w1 = (const float*)d_in[9];
    const float* e1b1 = (const float*)d_in[10];
    const float* e1w2 = (const float*)d_in[11];
    const float* e1b2 = (const float*)d_in[12];
    const float* e2w1 = (const float*)d_in[13];
    const float* e2b1 = (const float*)d_in[14];
    const float* e2w2 = (const float*)d_in[15];
    const float* e2b2 = (const float*)d_in[16];
    const float* wq  = (const float*)d_in[17];
    const float* bq  = (const float*)d_in[18];
    const float* wk  = (const float*)d_in[19];
    const float* bk  = (const float*)d_in[20];
    const float* wvv = (const float*)d_in[21];
    const float* bv  = (const float*)d_in[22];
    const float* wp  = (const float*)d_in[23];
    const float* bp  = (const float*)d_in[24];
    const float* wo  = (const float*)d_in[25];
    const float* bo  = (const float*)d_in[26];
    const float* nw1 = (const float*)d_in[27];
    const float* nb1 = (const float*)d_in[28];
    const float* nw2 = (const float*)d_in[29];
    const float* nb2 = (const float*)d_in[30];
    const float* nw3 = (const float*)d_in[31];
    const float* nb3 = (const float*)d_in[32];

    char* ws = (char*)d_ws;
    unsigned short* X = (unsigned short*)ws;               // 92,274,688 B
    float* F    = (float*)(ws + 92274688);
    float* POS  = F;                  // 1,441,792
    float* QT   = POS + 1441792;      // 4,194,304
    float* QP   = QT  + 4194304;      // 131,072
    float* QC   = QP  + 131072;       // 65,536
    float* a0   = QC  + 65536;        // 64
    float* b0g0 = a0  + 64;           // 4
    float* bvo  = b0g0 + 4;           // 64
    float* BEP  = bvo + 64;           // 192
    float* W2qG = BEP + 192;          // 4,096
    float* WvoG = W2qG + 4096;        // 4,096
    float* scqG = WvoG + 4096;        // 64
    unsigned short* W2P  = (unsigned short*)(scqG + 64);   // 12,288
    unsigned short* AqkP = W2P + 12288;                    // 4,096
    unsigned short* P3P  = AqkP + 4096;                    // 1,024
    unsigned short* WHP  = P3P + 1024;                     // 12,288

    k_prepA<<<43, 256, 0, stream>>>(emb, e0b2, e0w2, wq, bq, wp, bp, bk,
        wvv, bv, wo, bo, e1b2, e1w2, e2b2, e2w2, nw1, nw2,
        W2qG, WvoG, scqG, b0g0, bvo, BEP, W2P, WHP);
    k_prepB<<<4, 256, 0, stream>>>(W2qG, WvoG, scqG, wk, wp, bp, bk,
        AqkP, P3P, a0, WHP);
    k_encq<<<1920, 256, 0, stream>>>(pred, prey, obst, W2P, BEP,
        e0w1, e0b1, e1w1, e1b1, e2w1, e2b1,
        AqkP, a0, P3P, b0g0, X, POS, QT, QP, QC);
    k_attn<<<1024, 256, 0, stream>>>(X, POS, QT, QP, QC,
        WHP, bvo, nb1, nb2, nw3, nb3, (float*)d_out);
}

// Round 16
// 246.696 us; speedup vs baseline: 1.3141x; 1.3141x over previous
//
#include <hip/hip_runtime.h>
#include <math.h>

#define NB 512
#define NPQ 128
#define NY 1024
#define NO 256
#define NTOT 1408   // NPQ+NY+NO

typedef __attribute__((ext_vector_type(8))) short bf16x8;
typedef __attribute__((ext_vector_type(4))) float f32x4;

__device__ __forceinline__ unsigned short f2bf(float f) {
    unsigned int u = __float_as_uint(f);
    u += 0x7fffu + ((u >> 16) & 1u);   // RTNE
    return (unsigned short)(u >> 16);
}
__device__ __forceinline__ float bf2f(short s) {
    return __uint_as_float(((unsigned int)(unsigned short)s) << 16);
}

union U8  { bf16x8 v; unsigned long long u[2]; };
union U16 { bf16x8 v; uint4 u; };

// ============================================================================
// Kernel 0a: parallel weight folding, stage A (byte-identical to R13/R14).
// ============================================================================
__global__ __launch_bounds__(256) void k_prepA(
    const float* __restrict__ emb,  const float* __restrict__ e0b2,
    const float* __restrict__ e0w2, const float* __restrict__ wq,
    const float* __restrict__ bq,   const float* __restrict__ wp,
    const float* __restrict__ bp,   const float* __restrict__ bk,
    const float* __restrict__ wvv,  const float* __restrict__ bv,
    const float* __restrict__ wo,   const float* __restrict__ bo,
    const float* __restrict__ e1b2, const float* __restrict__ e1w2,
    const float* __restrict__ e2b2, const float* __restrict__ e2w2,
    const float* __restrict__ nw1,  const float* __restrict__ nw2,
    float* __restrict__ W2qG, float* __restrict__ WvoG,
    float* __restrict__ scqG, float* __restrict__ b0g0,
    float* __restrict__ bvo,  float* __restrict__ BEP,
    unsigned short* __restrict__ W2P, unsigned short* __restrict__ WHP)
{
    const int tid = threadIdx.x, blk = blockIdx.x;

    if (blk < 16) {
        const int idx = blk*256 + tid;
        const int h = idx >> 6, j = idx & 63;
        float s0 = 0.f, s1 = 0.f, s2 = 0.f, s3 = 0.f;
        #pragma unroll 4
        for (int e = 0; e < 64; e += 4) {
            s0 = fmaf(e0w2[h*64+e],   wq[(e  )*64+j], s0);
            s1 = fmaf(e0w2[h*64+e+1], wq[(e+1)*64+j], s1);
            s2 = fmaf(e0w2[h*64+e+2], wq[(e+2)*64+j], s2);
            s3 = fmaf(e0w2[h*64+e+3], wq[(e+3)*64+j], s3);
        }
        W2qG[idx] = (s0 + s1) + (s2 + s3);
    } else if (blk < 32) {
        const int idx = (blk-16)*256 + tid;
        const int e = idx >> 6, o = idx & 63;
        float s0 = 0.f, s1 = 0.f, s2 = 0.f, s3 = 0.f;
        #pragma unroll 4
        for (int d = 0; d < 64; d += 4) {
            s0 = fmaf(wvv[e*64+d],   wo[(d  )*64+o], s0);
            s1 = fmaf(wvv[e*64+d+1], wo[(d+1)*64+o], s1);
            s2 = fmaf(wvv[e*64+d+2], wo[(d+2)*64+o], s2);
            s3 = fmaf(wvv[e*64+d+3], wo[(d+3)*64+o], s3);
        }
        WvoG[idx] = (s0 + s1) + (s2 + s3);
    } else if (blk < 38) {
        const int idx = (blk-32)*256 + tid;
        if (idx < 1536) {
            const int t = idx >> 9, rem = idx & 511;
            const int mt = rem >> 7, rem2 = rem & 127;
            const int kh = rem2 >> 6, lane = rem2 & 63;
            const int quad = lane >> 4, lq = lane & 15;
            const float* w2 = (t == 0) ? e0w2 : ((t == 1) ? e1w2 : e2w2);
            unsigned short v[8];
            #pragma unroll
            for (int j = 0; j < 8; ++j)
                v[j] = f2bf(w2[(kh*32 + quad*8 + j)*64 + mt*16 + lq]);
            *(uint4*)&W2P[(size_t)idx*8] = make_uint4(
                (unsigned int)v[0] | ((unsigned int)v[1] << 16),
                (unsigned int)v[2] | ((unsigned int)v[3] << 16),
                (unsigned int)v[4] | ((unsigned int)v[5] << 16),
                (unsigned int)v[6] | ((unsigned int)v[7] << 16));
        }
    } else if (blk < 42) {
        const int idx = 512 + (blk-38)*256 + tid;
        const int l = idx >> 9, rem = idx & 511;
        const int mt = rem >> 7, rem2 = rem & 127;
        const int kh = rem2 >> 6, lane = rem2 & 63;
        const int quad = lane >> 4, lq = lane & 15;
        const float* W = (l == 1) ? nw1 : nw2;
        unsigned short v[8];
        #pragma unroll
        for (int j = 0; j < 8; ++j)
            v[j] = f2bf(W[(kh*32 + quad*8 + j)*64 + mt*16 + lq]);
        *(uint4*)&WHP[(size_t)idx*8] = make_uint4(
            (unsigned int)v[0] | ((unsigned int)v[1] << 16),
            (unsigned int)v[2] | ((unsigned int)v[3] << 16),
            (unsigned int)v[4] | ((unsigned int)v[5] << 16),
            (unsigned int)v[6] | ((unsigned int)v[7] << 16));
    } else {
        __shared__ float scq[64];
        if (tid < 64) {
            const int j = tid;
            float s = bq[j];
            for (int e = 0; e < 64; ++e) s += (e0b2[e] + emb[e]) * wq[e*64+j];
            scq[j] = s;
            scqG[j] = s;
        }
        if (tid >= 64 && tid < 128) {
            const int o = tid - 64;
            float s = bo[o];
            for (int d = 0; d < 64; ++d) s += bv[d] * wo[d*64+o];
            bvo[o] = s;
        }
        {
            const int i = tid - 64;
            if (i >= 64 && i < 256) {
                const int idx = i - 64;   // 0..191
                const int t = idx >> 6, d = idx & 63;
                const float* b2 = (t == 0) ? e0b2 : ((t == 1) ? e1b2 : e2b2);
                BEP[idx] = b2[d] + emb[t*64 + d];
            }
        }
        __syncthreads();
        if (tid == 0) {
            float s0 = 0.f, s1 = 0.f, s2 = 0.f;
            for (int j = 0; j < 64; ++j) {
                s0 += scq[j] * wp[j];
                s1 += scq[j] * wp[64+j];
                s2 += scq[j] * (bp[j] + bk[j]);
            }
            b0g0[0] = s0; b0g0[1] = s1; b0g0[2] = s2;
        }
    }
}

// ============================================================================
// Kernel 0b: stage B (byte-identical to R13/R14).
// ============================================================================
__global__ __launch_bounds__(256) void k_prepB(
    const float* __restrict__ W2qG, const float* __restrict__ WvoG,
    const float* __restrict__ scqG,
    const float* __restrict__ wk, const float* __restrict__ wp,
    const float* __restrict__ bp, const float* __restrict__ bk,
    unsigned short* __restrict__ AqkP, unsigned short* __restrict__ P3P,
    float* __restrict__ a0, unsigned short* __restrict__ WHP)
{
    const int tid = threadIdx.x, blk = blockIdx.x;

    if (blk < 2) {
        const int idx = blk*256 + tid;
        const int fi = idx >> 6, lane = idx & 63;
        const int mt = fi >> 1, kh = fi & 1;
        const int quad = lane >> 4, lq = lane & 15;
        const int d = mt*16 + lq;
        unsigned short v[8];
        #pragma unroll
        for (int jj = 0; jj < 8; ++jj) {
            const int h = kh*32 + quad*8 + jj;
            float s0 = 0.f, s1 = 0.f, s2 = 0.f, s3 = 0.f;
            #pragma unroll 4
            for (int j = 0; j < 64; j += 4) {
                const float4 a = *(const float4*)&W2qG[h*64 + j];
                const float4 b = *(const float4*)&wk[d*64 + j];
                s0 = fmaf(a.x, b.x, s0); s1 = fmaf(a.y, b.y, s1);
                s2 = fmaf(a.z, b.z, s2); s3 = fmaf(a.w, b.w, s3);
            }
            v[jj] = f2bf((s0 + s1) + (s2 + s3));
        }
        *(uint4*)&AqkP[(size_t)idx*8] = make_uint4(
            (unsigned int)v[0] | ((unsigned int)v[1] << 16),
            (unsigned int)v[2] | ((unsigned int)v[3] << 16),
            (unsigned int)v[4] | ((unsigned int)v[5] << 16),
            (unsigned int)v[6] | ((unsigned int)v[7] << 16));
    } else if (blk == 2) {
        if (tid < 128) {
            const int idx = tid;
            const int kh = idx >> 6, lane = idx & 63;
            const int quad = lane >> 4, lq = lane & 15;
            unsigned short v[8];
            #pragma unroll
            for (int jj = 0; jj < 8; ++jj) {
                const int h = kh*32 + quad*8 + jj;
                float val = 0.f;
                if (lq == 0 || lq == 1) {
                    float s0 = 0.f, s1 = 0.f;
                    #pragma unroll 8
                    for (int j = 0; j < 64; j += 2) {
                        s0 = fmaf(W2qG[h*64+j],   wp[lq*64+j],   s0);
                        s1 = fmaf(W2qG[h*64+j+1], wp[lq*64+j+1], s1);
                    }
                    val = s0 + s1;
                } else if (lq == 2) {
                    float s0 = 0.f, s1 = 0.f;
                    #pragma unroll 8
                    for (int j = 0; j < 64; j += 2) {
                        s0 = fmaf(W2qG[h*64+j],   bp[j]   + bk[j],   s0);
                        s1 = fmaf(W2qG[h*64+j+1], bp[j+1] + bk[j+1], s1);
                    }
                    val = s0 + s1;
                }
                v[jj] = f2bf(val);
            }
            *(uint4*)&P3P[(size_t)idx*8] = make_uint4(
                (unsigned int)v[0] | ((unsigned int)v[1] << 16),
                (unsigned int)v[2] | ((unsigned int)v[3] << 16),
                (unsigned int)v[4] | ((unsigned int)v[5] << 16),
                (unsigned int)v[6] | ((unsigned int)v[7] << 16));
        } else if (tid < 192) {
            const int d = tid - 128;
            float s0 = 0.f, s1 = 0.f, s2 = 0.f, s3 = 0.f;
            #pragma unroll 4
            for (int j = 0; j < 64; j += 4) {
                const float4 a = *(const float4*)&scqG[j];
                const float4 b = *(const float4*)&wk[d*64 + j];
                s0 = fmaf(a.x, b.x, s0); s1 = fmaf(a.y, b.y, s1);
                s2 = fmaf(a.z, b.z, s2); s3 = fmaf(a.w, b.w, s3);
            }
            a0[d] = (s0 + s1) + (s2 + s3);
        }
    } else {
        #pragma unroll
        for (int pass = 0; pass < 2; ++pass) {
            const int idx = pass*256 + tid;           // 0..511
            const int mt = idx >> 7, rem2 = idx & 127;
            const int kh = rem2 >> 6, lane = rem2 & 63;
            const int quad = lane >> 4, lq = lane & 15;
            unsigned short v[8];
            #pragma unroll
            for (int j = 0; j < 8; ++j)
                v[j] = f2bf(WvoG[(kh*32 + quad*8 + j)*64 + mt*16 + lq]);
            *(uint4*)&WHP[(size_t)idx*8] = make_uint4(
                (unsigned int)v[0] | ((unsigned int)v[1] << 16),
                (unsigned int)v[2] | ((unsigned int)v[3] << 16),
                (unsigned int)v[4] | ((unsigned int)v[5] << 16),
                (unsigned int)v[6] | ((unsigned int)v[7] << 16));
        }
    }
}

// ============================================================================
// Kernel 1: MERGED encoders + queries (byte-identical to R13/R14 — verified).
// ============================================================================
__global__ __launch_bounds__(256) void k_encq(
    const float* __restrict__ pred, const float* __restrict__ prey,
    const float* __restrict__ obst,
    const unsigned short* __restrict__ W2P, const float* __restrict__ BEP,
    const float* __restrict__ e0w1, const float* __restrict__ e0b1,
    const float* __restrict__ e1w1, const float* __restrict__ e1b1,
    const float* __restrict__ e2w1, const float* __restrict__ e2b1,
    const unsigned short* __restrict__ AqkP, const float* __restrict__ a0,
    const unsigned short* __restrict__ P3P,  const float* __restrict__ b0g0,
    unsigned short* __restrict__ X, float* __restrict__ POS,
    float* __restrict__ QT, float* __restrict__ QP, float* __restrict__ QC)
{
    const int tid = threadIdx.x, lane = tid & 63, w = tid >> 6;
    const int lq = lane & 15, quad = lane >> 4;
    __shared__ __align__(16) short sH[4][32][68];

    if (blockIdx.x < 1408) {
        const int blk = blockIdx.x;
        int type, lrow0, cin, lsh, nmask, nbase;
        const float *st, *w1, *b1;
        if (blk < 128)       { type=0; lrow0=blk*512;         st=pred; w1=e0w1; b1=e0b1; cin=2; lsh=7;  nmask=NPQ-1; nbase=0; }
        else if (blk < 1152) { type=1; lrow0=(blk-128)*512;   st=prey; w1=e1w1; b1=e1b1; cin=2; lsh=10; nmask=NY-1;  nbase=NPQ; }
        else                 { type=2; lrow0=(blk-1152)*512;  st=obst; w1=e2w1; b1=e2b1; cin=3; lsh=8;  nmask=NO-1;  nbase=NPQ+NY; }

        bf16x8 wfrag[4][2];
        #pragma unroll
        for (int mt = 0; mt < 4; ++mt)
            #pragma unroll
            for (int kh = 0; kh < 2; ++kh)
                wfrag[mt][kh] = *(const bf16x8*)&W2P[(size_t)(((type*4 + mt)*2 + kh)*64 + lane)*8];

        float4 be[4];
        #pragma unroll
        for (int mt = 0; mt < 4; ++mt)
            be[mt] = *(const float4*)&BEP[type*64 + mt*16 + quad*4];

        float b1v[2][8], w0v[2][8], w1v[2][8], w2v[2][8];
        #pragma unroll
        for (int kh = 0; kh < 2; ++kh) {
            const int k0 = kh*32 + quad*8;
            *(float4*)&b1v[kh][0] = *(const float4*)&b1[k0];
            *(float4*)&b1v[kh][4] = *(const float4*)&b1[k0+4];
            *(float4*)&w0v[kh][0] = *(const float4*)&w1[k0];
            *(float4*)&w0v[kh][4] = *(const float4*)&w1[k0+4];
            *(float4*)&w1v[kh][0] = *(const float4*)&w1[64+k0];
            *(float4*)&w1v[kh][4] = *(const float4*)&w1[64+k0+4];
            if (cin == 3) {
                *(float4*)&w2v[kh][0] = *(const float4*)&w1[128+k0];
                *(float4*)&w2v[kh][4] = *(const float4*)&w1[128+k0+4];
            }
        }

        #pragma unroll
        for (int k = 0; k < 4; ++k) {
            const int i = tid*4 + k;
            const int r = i >> 1, c = i & 1;
            const int lr = lrow0 + r;
            const int pb = lr >> lsh, n = nbase + (lr & nmask);
            POS[((size_t)pb*NTOT + n)*2 + c] = st[(size_t)lr*cin + c];
        }

        for (int rt = 0; rt < 8; ++rt) {
            const int lr = lrow0 + w*128 + rt*16 + lq;
            float s0, s1, s2 = 0.f;
            if (cin == 2) {
                const float2 sv = *(const float2*)&st[(size_t)lr*2];
                s0 = sv.x; s1 = sv.y;
            } else {
                const float2 sv = *(const float2*)&st[(size_t)lr*3];
                s0 = sv.x; s1 = sv.y; s2 = st[(size_t)lr*3 + 2];
            }
            bf16x8 hb[2];
            #pragma unroll
            for (int kh = 0; kh < 2; ++kh)
                #pragma unroll
                for (int j = 0; j < 8; ++j) {
                    float a = b1v[kh][j] + s0*w0v[kh][j] + s1*w1v[kh][j];
                    if (cin == 3) a += s2*w2v[kh][j];
                    hb[kh][j] = (short)f2bf(fmaxf(a, 0.f));
                }

            f32x4 acc[4];
            #pragma unroll
            for (int mt = 0; mt < 4; ++mt) acc[mt] = (f32x4){0.f,0.f,0.f,0.f};
            #pragma unroll
            for (int mt = 0; mt < 4; ++mt) {
                acc[mt] = __builtin_amdgcn_mfma_f32_16x16x32_bf16(wfrag[mt][0], hb[0], acc[mt], 0, 0, 0);
                acc[mt] = __builtin_amdgcn_mfma_f32_16x16x32_bf16(wfrag[mt][1], hb[1], acc[mt], 0, 0, 0);
            }

            const int bb = lr >> lsh, n = nbase + (lr & nmask);
            unsigned short* xbase = X + ((size_t)bb*NTOT + n)*64;
            #pragma unroll
            for (int mt = 0; mt < 4; ++mt) {
                const unsigned int u0 = (unsigned int)f2bf(acc[mt][0] + be[mt].x)
                                      | ((unsigned int)f2bf(acc[mt][1] + be[mt].y) << 16);
                const unsigned int u1 = (unsigned int)f2bf(acc[mt][2] + be[mt].z)
                                      | ((unsigned int)f2bf(acc[mt][3] + be[mt].w) << 16);
                *(uint2*)(xbase + mt*16 + quad*4) = make_uint2(u0, u1);
            }
        }
    } else {
        const int b = blockIdx.x - 1408;
        const float w1r0 = e0w1[lane], w1r1 = e0w1[64+lane], b1r = e0b1[lane];
        {
            const float* sp = pred + ((size_t)b*NPQ + w*32)*2;
            #pragma unroll
            for (int r = 0; r < 32; ++r) {
                const float a = b1r + sp[2*r]*w1r0 + sp[2*r+1]*w1r1;
                sH[w][r][lane] = (short)f2bf(fmaxf(a, 0.f));
            }
        }

        bf16x8 wfrag[4][2], a3[2];
        #pragma unroll
        for (int mt = 0; mt < 4; ++mt)
            #pragma unroll
            for (int kh = 0; kh < 2; ++kh)
                wfrag[mt][kh] = *(const bf16x8*)&AqkP[(size_t)((mt*2 + kh)*64 + lane)*8];
        #pragma unroll
        for (int kh = 0; kh < 2; ++kh)
            a3[kh] = *(const bf16x8*)&P3P[(size_t)(kh*64 + lane)*8];

        float4 a0r[4];
        #pragma unroll
        for (int mt = 0; mt < 4; ++mt) a0r[mt] = *(const float4*)&a0[mt*16 + quad*4];
        const float c0 = b0g0[0], c1 = b0g0[1], c2 = b0g0[2];

        __syncthreads();

        for (int bt = 0; bt < 2; ++bt) {
            U8 hb0, hb1;
            const short* hp = &sH[w][bt*16 + lq][0];
            hb0.u[0] = *(const unsigned long long*)(hp + quad*8);
            hb0.u[1] = *(const unsigned long long*)(hp + quad*8 + 4);
            hb1.u[0] = *(const unsigned long long*)(hp + 32 + quad*8);
            hb1.u[1] = *(const unsigned long long*)(hp + 32 + quad*8 + 4);

            f32x4 acc[4], acc3;
            #pragma unroll
            for (int mt = 0; mt < 4; ++mt) acc[mt] = (f32x4){0.f,0.f,0.f,0.f};
            acc3 = (f32x4){0.f,0.f,0.f,0.f};
            #pragma unroll
            for (int mt = 0; mt < 4; ++mt) {
                acc[mt] = __builtin_amdgcn_mfma_f32_16x16x32_bf16(wfrag[mt][0], hb0.v, acc[mt], 0, 0, 0);
                acc[mt] = __builtin_amdgcn_mfma_f32_16x16x32_bf16(wfrag[mt][1], hb1.v, acc[mt], 0, 0, 0);
            }
            acc3 = __builtin_amdgcn_mfma_f32_16x16x32_bf16(a3[0], hb0.v, acc3, 0, 0, 0);
            acc3 = __builtin_amdgcn_mfma_f32_16x16x32_bf16(a3[1], hb1.v, acc3, 0, 0, 0);

            const int row = b*NPQ + w*32 + bt*16 + lq;
            #pragma unroll
            for (int mt = 0; mt < 4; ++mt) {
                *(float4*)&QT[(size_t)row*64 + mt*16 + quad*4] = make_float4(
                    acc[mt][0] + a0r[mt].x, acc[mt][1] + a0r[mt].y,
                    acc[mt][2] + a0r[mt].z, acc[mt][3] + a0r[mt].w);
            }
            if (quad == 0) {
                const float qp0 = acc3[0] + c0, qp1 = acc3[1] + c1, qs = acc3[2] + c2;
                const float p0 = pred[(size_t)row*2], p1 = pred[(size_t)row*2 + 1];
                QP[(size_t)row*2]     = qp0;
                QP[(size_t)row*2 + 1] = qp1;
                QC[row] = qp0*p0 + qp1*p1 + qs;
            }
        }
    }
}

// ============================================================================
// Kernel 3: flash attention + FUSED output head (byte-identical to R14 —
// best measured config: 83 us, WRITE_SIZE 256 KB, absmax 0.0).
// ============================================================================
__global__ __launch_bounds__(256, 2) void k_attn(
    const unsigned short* __restrict__ X, const float* __restrict__ POS,
    const float* __restrict__ QT, const float* __restrict__ QP,
    const float* __restrict__ QC,
    const unsigned short* __restrict__ WHP,
    const float* __restrict__ bvo, const float* __restrict__ nb1,
    const float* __restrict__ nb2,
    const float* __restrict__ nw3, const float* __restrict__ nb3,
    float* __restrict__ OUT)
{
    const int tid = threadIdx.x, b = blockIdx.x;
    const int w = tid >> 6, lane = tid & 63, lq = lane & 15, quad = lane >> 4;

    __shared__ __align__(16) short sXc[2][64][68];   // [buf][d][key] (X^T)
    __shared__ __align__(16) short sP[4][32][68];    // per-wave [q][key]
    __shared__ __align__(16) short sA[128][68];      // head ping
    __shared__ __align__(16) short sB[128][68];      // head pong
    __shared__ float sw3[64];

    bf16x8 aq[2][2];
    #pragma unroll
    for (int qt = 0; qt < 2; ++qt) {
        const float* qrow = QT + ((size_t)b*NPQ + w*32 + qt*16 + lq)*64;
        #pragma unroll
        for (int kh = 0; kh < 2; ++kh)
            #pragma unroll
            for (int j = 0; j < 8; ++j)
                aq[qt][kh][j] = (short)f2bf(qrow[kh*32 + quad*8 + j]);
    }

    float qcr[2][4], qp0r[2][4], qp1r[2][4], lacc[2][4];
    f32x4 O[2][4];
    #pragma unroll
    for (int qt = 0; qt < 2; ++qt)
        #pragma unroll
        for (int i = 0; i < 4; ++i) {
            const size_t g = (size_t)b*NPQ + w*32 + qt*16 + quad*4 + i;
            qcr[qt][i]  = QC[g];
            qp0r[qt][i] = -QP[2*g];
            qp1r[qt][i] = -QP[2*g+1];
            lacc[qt][i] = 0.f;
        }
    #pragma unroll
    for (int qt = 0; qt < 2; ++qt)
        #pragma unroll
        for (int nt = 0; nt < 4; ++nt) O[qt][nt] = (f32x4){0.f,0.f,0.f,0.f};
    const float E = 0.180336884f;   // (1/sqrt(64)) * log2(e)

    const int skey = tid & 63, sd0 = (tid >> 6) * 16;

    for (int kt = 0; kt < 22; ++kt) {
        const int par = kt & 1;

        const unsigned short* gx = X + ((size_t)b*NTOT + kt*64 + skey)*64 + sd0;
        const uint4 t0 = *(const uint4*)(gx);
        const uint4 t1 = *(const uint4*)(gx + 8);

        if (kt > 0) {
            const int pb = par ^ 1;
            #pragma unroll
            for (int kc = 0; kc < 2; ++kc) {
                U8 pa[2];
                #pragma unroll
                for (int qt = 0; qt < 2; ++qt) {
                    const short* pp = &sP[w][qt*16 + lq][kc*32 + quad*8];
                    pa[qt].u[0] = *(const unsigned long long*)pp;
                    pa[qt].u[1] = *(const unsigned long long*)(pp + 4);
                }
                #pragma unroll
                for (int nt = 0; nt < 4; ++nt) {
                    U8 bv;
                    const short* xp = &sXc[pb][nt*16 + lq][kc*32 + quad*8];
                    bv.u[0] = *(const unsigned long long*)xp;
                    bv.u[1] = *(const unsigned long long*)(xp + 4);
                    O[0][nt] = __builtin_amdgcn_mfma_f32_16x16x32_bf16(pa[0].v, bv.v, O[0][nt], 0, 0, 0);
                    O[1][nt] = __builtin_amdgcn_mfma_f32_16x16x32_bf16(pa[1].v, bv.v, O[1][nt], 0, 0, 0);
                }
            }
        }

        __builtin_amdgcn_sched_barrier(0);

        #pragma unroll
        for (int nt = 0; nt < 4; ++nt) {
            U16 bx0, bx1;
            const unsigned short* xrow = X + ((size_t)b*NTOT + kt*64 + nt*16 + lq)*64;
            bx0.u = *(const uint4*)(xrow + quad*8);
            bx1.u = *(const uint4*)(xrow + 32 + quad*8);
            const float pos0 = POS[((size_t)b*NTOT + kt*64 + nt*16 + lq)*2];
            const float pos1 = POS[((size_t)b*NTOT + kt*64 + nt*16 + lq)*2 + 1];
            #pragma unroll
            for (int qt = 0; qt < 2; ++qt) {
                f32x4 sa = (f32x4){0.f,0.f,0.f,0.f};
                sa = __builtin_amdgcn_mfma_f32_16x16x32_bf16(aq[qt][0], bx0.v, sa, 0, 0, 0);
                sa = __builtin_amdgcn_mfma_f32_16x16x32_bf16(aq[qt][1], bx1.v, sa, 0, 0, 0);
                #pragma unroll
                for (int i = 0; i < 4; ++i) {
                    float s = sa[i] + qcr[qt][i];
                    s = fmaf(qp0r[qt][i], pos0, s);
                    s = fmaf(qp1r[qt][i], pos1, s);
                    const float p = exp2f(s * E);
                    lacc[qt][i] += p;
                    sP[w][qt*16 + quad*4 + i][nt*16 + lq] = (short)f2bf(p);
                }
            }
        }

        {
            unsigned short tmp[16];
            *(uint4*)tmp = t0; *(uint4*)(tmp+8) = t1;
            #pragma unroll
            for (int j = 0; j < 16; ++j) sXc[par][sd0+j][skey] = (short)tmp[j];
        }

        __syncthreads();
    }

    {
        #pragma unroll
        for (int kc = 0; kc < 2; ++kc) {
            U8 pa[2];
            #pragma unroll
            for (int qt = 0; qt < 2; ++qt) {
                const short* pp = &sP[w][qt*16 + lq][kc*32 + quad*8];
                pa[qt].u[0] = *(const unsigned long long*)pp;
                pa[qt].u[1] = *(const unsigned long long*)(pp + 4);
            }
            #pragma unroll
            for (int nt = 0; nt < 4; ++nt) {
                U8 bv;
                const short* xp = &sXc[1][nt*16 + lq][kc*32 + quad*8];
                bv.u[0] = *(const unsigned long long*)xp;
                bv.u[1] = *(const unsigned long long*)(xp + 4);
                O[0][nt] = __builtin_amdgcn_mfma_f32_16x16x32_bf16(pa[0].v, bv.v, O[0][nt], 0, 0, 0);
                O[1][nt] = __builtin_amdgcn_mfma_f32_16x16x32_bf16(pa[1].v, bv.v, O[1][nt], 0, 0, 0);
            }
        }
    }

    // ---- attention epilogue -> sA (bf16), same values as old OPRE path ----
    #pragma unroll
    for (int qt = 0; qt < 2; ++qt)
        #pragma unroll
        for (int i = 0; i < 4; ++i) {
            #pragma unroll
            for (int off = 1; off < 16; off <<= 1)
                lacc[qt][i] += __shfl_xor(lacc[qt][i], off);
            const float rl = 1.f / lacc[qt][i];
            const int row = w*32 + qt*16 + quad*4 + i;
            #pragma unroll
            for (int nt = 0; nt < 4; ++nt)
                sA[row][nt*16 + lq] = (short)f2bf(O[qt][nt][i] * rl);
        }
    if (tid < 64) sw3[tid] = nw3[tid];
    __syncthreads();   // sA complete before head reads (R2 lesson)

    // ---- fused head: 3 MFMA layers (verified k_head body) ----
    const float* Bs[3] = {bvo, nb1, nb2};
    for (int l = 0; l < 3; ++l) {
        bf16x8 wfrag[4][2];
        #pragma unroll
        for (int mt = 0; mt < 4; ++mt)
            #pragma unroll
            for (int kh = 0; kh < 2; ++kh)
                wfrag[mt][kh] = *(const bf16x8*)&WHP[(size_t)(((l*4 + mt)*2 + kh)*64 + lane)*8];
        const float* Bb = Bs[l];
        float be[4][4];
        #pragma unroll
        for (int mt = 0; mt < 4; ++mt)
            #pragma unroll
            for (int i = 0; i < 4; ++i) be[mt][i] = Bb[mt*16 + quad*4 + i];

        short (*src)[68] = (l & 1) ? sB : sA;
        short (*dst)[68] = (l & 1) ? sA : sB;
        const bool doRelu = (l >= 1);

        for (int bt = 0; bt < 2; ++bt) {
            U8 hb0, hb1;
            const short* hp = &src[w*32 + bt*16 + lq][0];
            hb0.u[0] = *(const unsigned long long*)(hp + quad*8);
            hb0.u[1] = *(const unsigned long long*)(hp + quad*8 + 4);
            hb1.u[0] = *(const unsigned long long*)(hp + 32 + quad*8);
            hb1.u[1] = *(const unsigned long long*)(hp + 32 + quad*8 + 4);

            f32x4 acc[4];
            #pragma unroll
            for (int mt = 0; mt < 4; ++mt) acc[mt] = (f32x4){0.f,0.f,0.f,0.f};
            #pragma unroll
            for (int mt = 0; mt < 4; ++mt) {
                acc[mt] = __builtin_amdgcn_mfma_f32_16x16x32_bf16(wfrag[mt][0], hb0.v, acc[mt], 0, 0, 0);
                acc[mt] = __builtin_amdgcn_mfma_f32_16x16x32_bf16(wfrag[mt][1], hb1.v, acc[mt], 0, 0, 0);
            }
            const int row = w*32 + bt*16 + lq;
            #pragma unroll
            for (int mt = 0; mt < 4; ++mt) {
                float v0 = acc[mt][0] + be[mt][0];
                float v1 = acc[mt][1] + be[mt][1];
                float v2 = acc[mt][2] + be[mt][2];
                float v3 = acc[mt][3] + be[mt][3];
                if (doRelu) {
                    v0 = fmaxf(v0, 0.f); v1 = fmaxf(v1, 0.f);
                    v2 = fmaxf(v2, 0.f); v3 = fmaxf(v3, 0.f);
                }
                const unsigned int u0 = (unsigned int)f2bf(v0) | ((unsigned int)f2bf(v1) << 16);
                const unsigned int u1 = (unsigned int)f2bf(v2) | ((unsigned int)f2bf(v3) << 16);
                *(uint2*)&dst[row][mt*16 + quad*4] = make_uint2(u0, u1);
            }
        }
        __syncthreads();
    }

    if (tid < 128) {
        const int row = tid;
        float acc = nb3[0];
        #pragma unroll 16
        for (int d = 0; d < 64; ++d) acc += bf2f(sB[row][d]) * sw3[d];
        OUT[(size_t)b*NPQ + row] = tanhf(acc);
    }
}

// ============================================================================
extern "C" void kernel_launch(void* const* d_in, const int* in_sizes, int n_in,
                              void* d_out, int out_size, void* d_ws, size_t ws_size,
                              hipStream_t stream)
{
    const float* pred = (const float*)d_in[0];
    const float* prey = (const float*)d_in[1];
    const float* obst = (const float*)d_in[2];
    const float* emb  = (const float*)d_in[4];
    const float* e0w1 = (const float*)d_in[5];
    const float* e0b1 = (const float*)d_in[6];
    const float* e0w2 = (const float*)d_in[7];
    const float* e0b2 = (const float*)d_in[8];
    const float* e1w1 = (const float*)d_in[9];
    const float* e1b1 = (const float*)d_in[10];
    const float* e1w2 = (const float*)d_in[11];
    const float* e1b2 = (const float*)d_in[12];
    const float* e2w1 = (const float*)d_in[13];
    const float* e2b1 = (const float*)d_in[14];
    const float* e2w2 = (const float*)d_in[15];
    const float* e2b2 = (const float*)d_in[16];
    const float* wq  = (const float*)d_in[17];
    const float* bq  = (const float*)d_in[18];
    const float* wk  = (const float*)d_in[19];
    const float* bk  = (const float*)d_in[20];
    const float* wvv = (const float*)d_in[21];
    const float* bv  = (const float*)d_in[22];
    const float* wp  = (const float*)d_in[23];
    const float* bp  = (const float*)d_in[24];
    const float* wo  = (const float*)d_in[25];
    const float* bo  = (const float*)d_in[26];
    const float* nw1 = (const float*)d_in[27];
    const float* nb1 = (const float*)d_in[28];
    const float* nw2 = (const float*)d_in[29];
    const float* nb2 = (const float*)d_in[30];
    const float* nw3 = (const float*)d_in[31];
    const float* nb3 = (const float*)d_in[32];

    char* ws = (char*)d_ws;
    unsigned short* X = (unsigned short*)ws;               // 92,274,688 B
    float* F    = (float*)(ws + 92274688);
    float* POS  = F;                  // 1,441,792
    float* QT   = POS + 1441792;      // 4,194,304
    float* QP   = QT  + 4194304;      // 131,072
    float* QC   = QP  + 131072;       // 65,536
    float* a0   = QC  + 65536;        // 64
    float* b0g0 = a0  + 64;           // 4
    float* bvo  = b0g0 + 4;           // 64
    float* BEP  = bvo + 64;           // 192
    float* W2qG = BEP + 192;          // 4,096
    float* WvoG = W2qG + 4096;        // 4,096
    float* scqG = WvoG + 4096;        // 64
    unsigned short* W2P  = (unsigned short*)(scqG + 64);   // 12,288
    unsigned short* AqkP = W2P + 12288;                    // 4,096
    unsigned short* P3P  = AqkP + 4096;                    // 1,024
    unsigned short* WHP  = P3P + 1024;                     // 12,288

    k_prepA<<<43, 256, 0, stream>>>(emb, e0b2, e0w2, wq, bq, wp, bp, bk,
        wvv, bv, wo, bo, e1b2, e1w2, e2b2, e2w2, nw1, nw2,
        W2qG, WvoG, scqG, b0g0, bvo, BEP, W2P, WHP);
    k_prepB<<<4, 256, 0, stream>>>(W2qG, WvoG, scqG, wk, wp, bp, bk,
        AqkP, P3P, a0, WHP);
    k_encq<<<1920, 256, 0, stream>>>(pred, prey, obst, W2P, BEP,
        e0w1, e0b1, e1w1, e1b1, e2w1, e2b1,
        AqkP, a0, P3P, b0g0, X, POS, QT, QP, QC);
    k_attn<<<512, 256, 0, stream>>>(X, POS, QT, QP, QC,
        WHP, bvo, nb1, nb2, nw3, nb3, (float*)d_out);
}

// Round 17
// 242.867 us; speedup vs baseline: 1.3348x; 1.0158x over previous
//
#include <hip/hip_runtime.h>
#include <math.h>

#define NB 512
#define NPQ 128
#define NY 1024
#define NO 256
#define NTOT 1408   // NPQ+NY+NO
#define SCALE_E 0.180336884f   // (1/sqrt(64)) * log2(e), folded upstream (R17)

typedef __attribute__((ext_vector_type(8))) short bf16x8;
typedef __attribute__((ext_vector_type(4))) float f32x4;

__device__ __forceinline__ unsigned short f2bf(float f) {
    unsigned int u = __float_as_uint(f);
    u += 0x7fffu + ((u >> 16) & 1u);   // RTNE
    return (unsigned short)(u >> 16);
}
__device__ __forceinline__ float bf2f(short s) {
    return __uint_as_float(((unsigned int)(unsigned short)s) << 16);
}

union U8  { bf16x8 v; unsigned long long u[2]; };
union U16 { bf16x8 v; uint4 u; };

// ============================================================================
// Kernel 0a: parallel weight folding, stage A. R17: b0g0 pre-scaled by E.
// ============================================================================
__global__ __launch_bounds__(256) void k_prepA(
    const float* __restrict__ emb,  const float* __restrict__ e0b2,
    const float* __restrict__ e0w2, const float* __restrict__ wq,
    const float* __restrict__ bq,   const float* __restrict__ wp,
    const float* __restrict__ bp,   const float* __restrict__ bk,
    const float* __restrict__ wvv,  const float* __restrict__ bv,
    const float* __restrict__ wo,   const float* __restrict__ bo,
    const float* __restrict__ e1b2, const float* __restrict__ e1w2,
    const float* __restrict__ e2b2, const float* __restrict__ e2w2,
    const float* __restrict__ nw1,  const float* __restrict__ nw2,
    float* __restrict__ W2qG, float* __restrict__ WvoG,
    float* __restrict__ scqG, float* __restrict__ b0g0,
    float* __restrict__ bvo,  float* __restrict__ BEP,
    unsigned short* __restrict__ W2P, unsigned short* __restrict__ WHP)
{
    const int tid = threadIdx.x, blk = blockIdx.x;

    if (blk < 16) {
        const int idx = blk*256 + tid;
        const int h = idx >> 6, j = idx & 63;
        float s0 = 0.f, s1 = 0.f, s2 = 0.f, s3 = 0.f;
        #pragma unroll 4
        for (int e = 0; e < 64; e += 4) {
            s0 = fmaf(e0w2[h*64+e],   wq[(e  )*64+j], s0);
            s1 = fmaf(e0w2[h*64+e+1], wq[(e+1)*64+j], s1);
            s2 = fmaf(e0w2[h*64+e+2], wq[(e+2)*64+j], s2);
            s3 = fmaf(e0w2[h*64+e+3], wq[(e+3)*64+j], s3);
        }
        W2qG[idx] = (s0 + s1) + (s2 + s3);
    } else if (blk < 32) {
        const int idx = (blk-16)*256 + tid;
        const int e = idx >> 6, o = idx & 63;
        float s0 = 0.f, s1 = 0.f, s2 = 0.f, s3 = 0.f;
        #pragma unroll 4
        for (int d = 0; d < 64; d += 4) {
            s0 = fmaf(wvv[e*64+d],   wo[(d  )*64+o], s0);
            s1 = fmaf(wvv[e*64+d+1], wo[(d+1)*64+o], s1);
            s2 = fmaf(wvv[e*64+d+2], wo[(d+2)*64+o], s2);
            s3 = fmaf(wvv[e*64+d+3], wo[(d+3)*64+o], s3);
        }
        WvoG[idx] = (s0 + s1) + (s2 + s3);
    } else if (blk < 38) {
        const int idx = (blk-32)*256 + tid;
        if (idx < 1536) {
            const int t = idx >> 9, rem = idx & 511;
            const int mt = rem >> 7, rem2 = rem & 127;
            const int kh = rem2 >> 6, lane = rem2 & 63;
            const int quad = lane >> 4, lq = lane & 15;
            const float* w2 = (t == 0) ? e0w2 : ((t == 1) ? e1w2 : e2w2);
            unsigned short v[8];
            #pragma unroll
            for (int j = 0; j < 8; ++j)
                v[j] = f2bf(w2[(kh*32 + quad*8 + j)*64 + mt*16 + lq]);
            *(uint4*)&W2P[(size_t)idx*8] = make_uint4(
                (unsigned int)v[0] | ((unsigned int)v[1] << 16),
                (unsigned int)v[2] | ((unsigned int)v[3] << 16),
                (unsigned int)v[4] | ((unsigned int)v[5] << 16),
                (unsigned int)v[6] | ((unsigned int)v[7] << 16));
        }
    } else if (blk < 42) {
        const int idx = 512 + (blk-38)*256 + tid;
        const int l = idx >> 9, rem = idx & 511;
        const int mt = rem >> 7, rem2 = rem & 127;
        const int kh = rem2 >> 6, lane = rem2 & 63;
        const int quad = lane >> 4, lq = lane & 15;
        const float* W = (l == 1) ? nw1 : nw2;
        unsigned short v[8];
        #pragma unroll
        for (int j = 0; j < 8; ++j)
            v[j] = f2bf(W[(kh*32 + quad*8 + j)*64 + mt*16 + lq]);
        *(uint4*)&WHP[(size_t)idx*8] = make_uint4(
            (unsigned int)v[0] | ((unsigned int)v[1] << 16),
            (unsigned int)v[2] | ((unsigned int)v[3] << 16),
            (unsigned int)v[4] | ((unsigned int)v[5] << 16),
            (unsigned int)v[6] | ((unsigned int)v[7] << 16));
    } else {
        __shared__ float scq[64];
        if (tid < 64) {
            const int j = tid;
            float s = bq[j];
            for (int e = 0; e < 64; ++e) s += (e0b2[e] + emb[e]) * wq[e*64+j];
            scq[j] = s;
            scqG[j] = s;
        }
        if (tid >= 64 && tid < 128) {
            const int o = tid - 64;
            float s = bo[o];
            for (int d = 0; d < 64; ++d) s += bv[d] * wo[d*64+o];
            bvo[o] = s;
        }
        {
            const int i = tid - 64;
            if (i >= 64 && i < 256) {
                const int idx = i - 64;   // 0..191
                const int t = idx >> 6, d = idx & 63;
                const float* b2 = (t == 0) ? e0b2 : ((t == 1) ? e1b2 : e2b2);
                BEP[idx] = b2[d] + emb[t*64 + d];
            }
        }
        __syncthreads();
        if (tid == 0) {
            float s0 = 0.f, s1 = 0.f, s2 = 0.f;
            for (int j = 0; j < 64; ++j) {
                s0 += scq[j] * wp[j];
                s1 += scq[j] * wp[64+j];
                s2 += scq[j] * (bp[j] + bk[j]);
            }
            b0g0[0] = SCALE_E * s0;    // R17: E folded upstream
            b0g0[1] = SCALE_E * s1;
            b0g0[2] = SCALE_E * s2;
        }
    }
}

// ============================================================================
// Kernel 0b: stage B. R17: AqkP / P3P / a0 pre-scaled by E.
// ============================================================================
__global__ __launch_bounds__(256) void k_prepB(
    const float* __restrict__ W2qG, const float* __restrict__ WvoG,
    const float* __restrict__ scqG,
    const float* __restrict__ wk, const float* __restrict__ wp,
    const float* __restrict__ bp, const float* __restrict__ bk,
    unsigned short* __restrict__ AqkP, unsigned short* __restrict__ P3P,
    float* __restrict__ a0, unsigned short* __restrict__ WHP)
{
    const int tid = threadIdx.x, blk = blockIdx.x;

    if (blk < 2) {
        const int idx = blk*256 + tid;
        const int fi = idx >> 6, lane = idx & 63;
        const int mt = fi >> 1, kh = fi & 1;
        const int quad = lane >> 4, lq = lane & 15;
        const int d = mt*16 + lq;
        unsigned short v[8];
        #pragma unroll
        for (int jj = 0; jj < 8; ++jj) {
            const int h = kh*32 + quad*8 + jj;
            float s0 = 0.f, s1 = 0.f, s2 = 0.f, s3 = 0.f;
            #pragma unroll 4
            for (int j = 0; j < 64; j += 4) {
                const float4 a = *(const float4*)&W2qG[h*64 + j];
                const float4 b = *(const float4*)&wk[d*64 + j];
                s0 = fmaf(a.x, b.x, s0); s1 = fmaf(a.y, b.y, s1);
                s2 = fmaf(a.z, b.z, s2); s3 = fmaf(a.w, b.w, s3);
            }
            v[jj] = f2bf(SCALE_E * ((s0 + s1) + (s2 + s3)));   // R17
        }
        *(uint4*)&AqkP[(size_t)idx*8] = make_uint4(
            (unsigned int)v[0] | ((unsigned int)v[1] << 16),
            (unsigned int)v[2] | ((unsigned int)v[3] << 16),
            (unsigned int)v[4] | ((unsigned int)v[5] << 16),
            (unsigned int)v[6] | ((unsigned int)v[7] << 16));
    } else if (blk == 2) {
        if (tid < 128) {
            const int idx = tid;
            const int kh = idx >> 6, lane = idx & 63;
            const int quad = lane >> 4, lq = lane & 15;
            unsigned short v[8];
            #pragma unroll
            for (int jj = 0; jj < 8; ++jj) {
                const int h = kh*32 + quad*8 + jj;
                float val = 0.f;
                if (lq == 0 || lq == 1) {
                    float s0 = 0.f, s1 = 0.f;
                    #pragma unroll 8
                    for (int j = 0; j < 64; j += 2) {
                        s0 = fmaf(W2qG[h*64+j],   wp[lq*64+j],   s0);
                        s1 = fmaf(W2qG[h*64+j+1], wp[lq*64+j+1], s1);
                    }
                    val = s0 + s1;
                } else if (lq == 2) {
                    float s0 = 0.f, s1 = 0.f;
                    #pragma unroll 8
                    for (int j = 0; j < 64; j += 2) {
                        s0 = fmaf(W2qG[h*64+j],   bp[j]   + bk[j],   s0);
                        s1 = fmaf(W2qG[h*64+j+1], bp[j+1] + bk[j+1], s1);
                    }
                    val = s0 + s1;
                }
                v[jj] = f2bf(SCALE_E * val);   // R17
            }
            *(uint4*)&P3P[(size_t)idx*8] = make_uint4(
                (unsigned int)v[0] | ((unsigned int)v[1] << 16),
                (unsigned int)v[2] | ((unsigned int)v[3] << 16),
                (unsigned int)v[4] | ((unsigned int)v[5] << 16),
                (unsigned int)v[6] | ((unsigned int)v[7] << 16));
        } else if (tid < 192) {
            const int d = tid - 128;
            float s0 = 0.f, s1 = 0.f, s2 = 0.f, s3 = 0.f;
            #pragma unroll 4
            for (int j = 0; j < 64; j += 4) {
                const float4 a = *(const float4*)&scqG[j];
                const float4 b = *(const float4*)&wk[d*64 + j];
                s0 = fmaf(a.x, b.x, s0); s1 = fmaf(a.y, b.y, s1);
                s2 = fmaf(a.z, b.z, s2); s3 = fmaf(a.w, b.w, s3);
            }
            a0[d] = SCALE_E * ((s0 + s1) + (s2 + s3));   // R17
        }
    } else {
        #pragma unroll
        for (int pass = 0; pass < 2; ++pass) {
            const int idx = pass*256 + tid;           // 0..511
            const int mt = idx >> 7, rem2 = idx & 127;
            const int kh = rem2 >> 6, lane = rem2 & 63;
            const int quad = lane >> 4, lq = lane & 15;
            unsigned short v[8];
            #pragma unroll
            for (int j = 0; j < 8; ++j)
                v[j] = f2bf(WvoG[(kh*32 + quad*8 + j)*64 + mt*16 + lq]);
            *(uint4*)&WHP[(size_t)idx*8] = make_uint4(
                (unsigned int)v[0] | ((unsigned int)v[1] << 16),
                (unsigned int)v[2] | ((unsigned int)v[3] << 16),
                (unsigned int)v[4] | ((unsigned int)v[5] << 16),
                (unsigned int)v[6] | ((unsigned int)v[7] << 16));
        }
    }
}

// ============================================================================
// Kernel 1: MERGED encoders + queries (byte-identical to R13/R14/R16 —
// verified; it consumes the pre-scaled AqkP/P3P/a0/b0g0 transparently, so
// QT/QP/QC come out E-scaled coherently).
// ============================================================================
__global__ __launch_bounds__(256) void k_encq(
    const float* __restrict__ pred, const float* __restrict__ prey,
    const float* __restrict__ obst,
    const unsigned short* __restrict__ W2P, const float* __restrict__ BEP,
    const float* __restrict__ e0w1, const float* __restrict__ e0b1,
    const float* __restrict__ e1w1, const float* __restrict__ e1b1,
    const float* __restrict__ e2w1, const float* __restrict__ e2b1,
    const unsigned short* __restrict__ AqkP, const float* __restrict__ a0,
    const unsigned short* __restrict__ P3P,  const float* __restrict__ b0g0,
    unsigned short* __restrict__ X, float* __restrict__ POS,
    float* __restrict__ QT, float* __restrict__ QP, float* __restrict__ QC)
{
    const int tid = threadIdx.x, lane = tid & 63, w = tid >> 6;
    const int lq = lane & 15, quad = lane >> 4;
    __shared__ __align__(16) short sH[4][32][68];

    if (blockIdx.x < 1408) {
        const int blk = blockIdx.x;
        int type, lrow0, cin, lsh, nmask, nbase;
        const float *st, *w1, *b1;
        if (blk < 128)       { type=0; lrow0=blk*512;         st=pred; w1=e0w1; b1=e0b1; cin=2; lsh=7;  nmask=NPQ-1; nbase=0; }
        else if (blk < 1152) { type=1; lrow0=(blk-128)*512;   st=prey; w1=e1w1; b1=e1b1; cin=2; lsh=10; nmask=NY-1;  nbase=NPQ; }
        else                 { type=2; lrow0=(blk-1152)*512;  st=obst; w1=e2w1; b1=e2b1; cin=3; lsh=8;  nmask=NO-1;  nbase=NPQ+NY; }

        bf16x8 wfrag[4][2];
        #pragma unroll
        for (int mt = 0; mt < 4; ++mt)
            #pragma unroll
            for (int kh = 0; kh < 2; ++kh)
                wfrag[mt][kh] = *(const bf16x8*)&W2P[(size_t)(((type*4 + mt)*2 + kh)*64 + lane)*8];

        float4 be[4];
        #pragma unroll
        for (int mt = 0; mt < 4; ++mt)
            be[mt] = *(const float4*)&BEP[type*64 + mt*16 + quad*4];

        float b1v[2][8], w0v[2][8], w1v[2][8], w2v[2][8];
        #pragma unroll
        for (int kh = 0; kh < 2; ++kh) {
            const int k0 = kh*32 + quad*8;
            *(float4*)&b1v[kh][0] = *(const float4*)&b1[k0];
            *(float4*)&b1v[kh][4] = *(const float4*)&b1[k0+4];
            *(float4*)&w0v[kh][0] = *(const float4*)&w1[k0];
            *(float4*)&w0v[kh][4] = *(const float4*)&w1[k0+4];
            *(float4*)&w1v[kh][0] = *(const float4*)&w1[64+k0];
            *(float4*)&w1v[kh][4] = *(const float4*)&w1[64+k0+4];
            if (cin == 3) {
                *(float4*)&w2v[kh][0] = *(const float4*)&w1[128+k0];
                *(float4*)&w2v[kh][4] = *(const float4*)&w1[128+k0+4];
            }
        }

        #pragma unroll
        for (int k = 0; k < 4; ++k) {
            const int i = tid*4 + k;
            const int r = i >> 1, c = i & 1;
            const int lr = lrow0 + r;
            const int pb = lr >> lsh, n = nbase + (lr & nmask);
            POS[((size_t)pb*NTOT + n)*2 + c] = st[(size_t)lr*cin + c];
        }

        for (int rt = 0; rt < 8; ++rt) {
            const int lr = lrow0 + w*128 + rt*16 + lq;
            float s0, s1, s2 = 0.f;
            if (cin == 2) {
                const float2 sv = *(const float2*)&st[(size_t)lr*2];
                s0 = sv.x; s1 = sv.y;
            } else {
                const float2 sv = *(const float2*)&st[(size_t)lr*3];
                s0 = sv.x; s1 = sv.y; s2 = st[(size_t)lr*3 + 2];
            }
            bf16x8 hb[2];
            #pragma unroll
            for (int kh = 0; kh < 2; ++kh)
                #pragma unroll
                for (int j = 0; j < 8; ++j) {
                    float a = b1v[kh][j] + s0*w0v[kh][j] + s1*w1v[kh][j];
                    if (cin == 3) a += s2*w2v[kh][j];
                    hb[kh][j] = (short)f2bf(fmaxf(a, 0.f));
                }

            f32x4 acc[4];
            #pragma unroll
            for (int mt = 0; mt < 4; ++mt) acc[mt] = (f32x4){0.f,0.f,0.f,0.f};
            #pragma unroll
            for (int mt = 0; mt < 4; ++mt) {
                acc[mt] = __builtin_amdgcn_mfma_f32_16x16x32_bf16(wfrag[mt][0], hb[0], acc[mt], 0, 0, 0);
                acc[mt] = __builtin_amdgcn_mfma_f32_16x16x32_bf16(wfrag[mt][1], hb[1], acc[mt], 0, 0, 0);
            }

            const int bb = lr >> lsh, n = nbase + (lr & nmask);
            unsigned short* xbase = X + ((size_t)bb*NTOT + n)*64;
            #pragma unroll
            for (int mt = 0; mt < 4; ++mt) {
                const unsigned int u0 = (unsigned int)f2bf(acc[mt][0] + be[mt].x)
                                      | ((unsigned int)f2bf(acc[mt][1] + be[mt].y) << 16);
                const unsigned int u1 = (unsigned int)f2bf(acc[mt][2] + be[mt].z)
                                      | ((unsigned int)f2bf(acc[mt][3] + be[mt].w) << 16);
                *(uint2*)(xbase + mt*16 + quad*4) = make_uint2(u0, u1);
            }
        }
    } else {
        const int b = blockIdx.x - 1408;
        const float w1r0 = e0w1[lane], w1r1 = e0w1[64+lane], b1r = e0b1[lane];
        {
            const float* sp = pred + ((size_t)b*NPQ + w*32)*2;
            #pragma unroll
            for (int r = 0; r < 32; ++r) {
                const float a = b1r + sp[2*r]*w1r0 + sp[2*r+1]*w1r1;
                sH[w][r][lane] = (short)f2bf(fmaxf(a, 0.f));
            }
        }

        bf16x8 wfrag[4][2], a3[2];
        #pragma unroll
        for (int mt = 0; mt < 4; ++mt)
            #pragma unroll
            for (int kh = 0; kh < 2; ++kh)
                wfrag[mt][kh] = *(const bf16x8*)&AqkP[(size_t)((mt*2 + kh)*64 + lane)*8];
        #pragma unroll
        for (int kh = 0; kh < 2; ++kh)
            a3[kh] = *(const bf16x8*)&P3P[(size_t)(kh*64 + lane)*8];

        float4 a0r[4];
        #pragma unroll
        for (int mt = 0; mt < 4; ++mt) a0r[mt] = *(const float4*)&a0[mt*16 + quad*4];
        const float c0 = b0g0[0], c1 = b0g0[1], c2 = b0g0[2];

        __syncthreads();

        for (int bt = 0; bt < 2; ++bt) {
            U8 hb0, hb1;
            const short* hp = &sH[w][bt*16 + lq][0];
            hb0.u[0] = *(const unsigned long long*)(hp + quad*8);
            hb0.u[1] = *(const unsigned long long*)(hp + quad*8 + 4);
            hb1.u[0] = *(const unsigned long long*)(hp + 32 + quad*8);
            hb1.u[1] = *(const unsigned long long*)(hp + 32 + quad*8 + 4);

            f32x4 acc[4], acc3;
            #pragma unroll
            for (int mt = 0; mt < 4; ++mt) acc[mt] = (f32x4){0.f,0.f,0.f,0.f};
            acc3 = (f32x4){0.f,0.f,0.f,0.f};
            #pragma unroll
            for (int mt = 0; mt < 4; ++mt) {
                acc[mt] = __builtin_amdgcn_mfma_f32_16x16x32_bf16(wfrag[mt][0], hb0.v, acc[mt], 0, 0, 0);
                acc[mt] = __builtin_amdgcn_mfma_f32_16x16x32_bf16(wfrag[mt][1], hb1.v, acc[mt], 0, 0, 0);
            }
            acc3 = __builtin_amdgcn_mfma_f32_16x16x32_bf16(a3[0], hb0.v, acc3, 0, 0, 0);
            acc3 = __builtin_amdgcn_mfma_f32_16x16x32_bf16(a3[1], hb1.v, acc3, 0, 0, 0);

            const int row = b*NPQ + w*32 + bt*16 + lq;
            #pragma unroll
            for (int mt = 0; mt < 4; ++mt) {
                *(float4*)&QT[(size_t)row*64 + mt*16 + quad*4] = make_float4(
                    acc[mt][0] + a0r[mt].x, acc[mt][1] + a0r[mt].y,
                    acc[mt][2] + a0r[mt].z, acc[mt][3] + a0r[mt].w);
            }
            if (quad == 0) {
                const float qp0 = acc3[0] + c0, qp1 = acc3[1] + c1, qs = acc3[2] + c2;
                const float p0 = pred[(size_t)row*2], p1 = pred[(size_t)row*2 + 1];
                QP[(size_t)row*2]     = qp0;
                QP[(size_t)row*2 + 1] = qp1;
                QC[row] = qp0*p0 + qp1*p1 + qs;
            }
        }
    }
}

// ============================================================================
// Kernel 3: flash attention + fused head (R14 structure — best measured).
// R17 deltas only: (a) QT/QP/QC arrive E-scaled => p = exp2f(s) directly;
// (b) qcr folded into the S-MFMA C-initializer (C/D reg i = row quad*4+i,
// which is exactly qcr's index) — removes 1 mul + 1 add per score.
// ============================================================================
__global__ __launch_bounds__(256, 2) void k_attn(
    const unsigned short* __restrict__ X, const float* __restrict__ POS,
    const float* __restrict__ QT, const float* __restrict__ QP,
    const float* __restrict__ QC,
    const unsigned short* __restrict__ WHP,
    const float* __restrict__ bvo, const float* __restrict__ nb1,
    const float* __restrict__ nb2,
    const float* __restrict__ nw3, const float* __restrict__ nb3,
    float* __restrict__ OUT)
{
    const int tid = threadIdx.x, b = blockIdx.x;
    const int w = tid >> 6, lane = tid & 63, lq = lane & 15, quad = lane >> 4;

    __shared__ __align__(16) short sXc[2][64][68];   // [buf][d][key] (X^T)
    __shared__ __align__(16) short sP[4][32][68];    // per-wave [q][key]
    __shared__ __align__(16) short sA[128][68];      // head ping
    __shared__ __align__(16) short sB[128][68];      // head pong
    __shared__ float sw3[64];

    bf16x8 aq[2][2];
    #pragma unroll
    for (int qt = 0; qt < 2; ++qt) {
        const float* qrow = QT + ((size_t)b*NPQ + w*32 + qt*16 + lq)*64;
        #pragma unroll
        for (int kh = 0; kh < 2; ++kh)
            #pragma unroll
            for (int j = 0; j < 8; ++j)
                aq[qt][kh][j] = (short)f2bf(qrow[kh*32 + quad*8 + j]);
    }

    float qp0r[2][4], qp1r[2][4], lacc[2][4];
    f32x4 qcv[2];     // R17: C-initializer holding qcr per accumulator reg
    f32x4 O[2][4];
    #pragma unroll
    for (int qt = 0; qt < 2; ++qt)
        #pragma unroll
        for (int i = 0; i < 4; ++i) {
            const size_t g = (size_t)b*NPQ + w*32 + qt*16 + quad*4 + i;
            qcv[qt][i]  = QC[g];
            qp0r[qt][i] = -QP[2*g];
            qp1r[qt][i] = -QP[2*g+1];
            lacc[qt][i] = 0.f;
        }
    #pragma unroll
    for (int qt = 0; qt < 2; ++qt)
        #pragma unroll
        for (int nt = 0; nt < 4; ++nt) O[qt][nt] = (f32x4){0.f,0.f,0.f,0.f};

    const int skey = tid & 63, sd0 = (tid >> 6) * 16;

    for (int kt = 0; kt < 22; ++kt) {
        const int par = kt & 1;

        const unsigned short* gx = X + ((size_t)b*NTOT + kt*64 + skey)*64 + sd0;
        const uint4 t0 = *(const uint4*)(gx);
        const uint4 t1 = *(const uint4*)(gx + 8);

        if (kt > 0) {
            const int pb = par ^ 1;
            #pragma unroll
            for (int kc = 0; kc < 2; ++kc) {
                U8 pa[2];
                #pragma unroll
                for (int qt = 0; qt < 2; ++qt) {
                    const short* pp = &sP[w][qt*16 + lq][kc*32 + quad*8];
                    pa[qt].u[0] = *(const unsigned long long*)pp;
                    pa[qt].u[1] = *(const unsigned long long*)(pp + 4);
                }
                #pragma unroll
                for (int nt = 0; nt < 4; ++nt) {
                    U8 bv;
                    const short* xp = &sXc[pb][nt*16 + lq][kc*32 + quad*8];
                    bv.u[0] = *(const unsigned long long*)xp;
                    bv.u[1] = *(const unsigned long long*)(xp + 4);
                    O[0][nt] = __builtin_amdgcn_mfma_f32_16x16x32_bf16(pa[0].v, bv.v, O[0][nt], 0, 0, 0);
                    O[1][nt] = __builtin_amdgcn_mfma_f32_16x16x32_bf16(pa[1].v, bv.v, O[1][nt], 0, 0, 0);
                }
            }
        }

        __builtin_amdgcn_sched_barrier(0);

        #pragma unroll
        for (int nt = 0; nt < 4; ++nt) {
            U16 bx0, bx1;
            const unsigned short* xrow = X + ((size_t)b*NTOT + kt*64 + nt*16 + lq)*64;
            bx0.u = *(const uint4*)(xrow + quad*8);
            bx1.u = *(const uint4*)(xrow + 32 + quad*8);
            const float pos0 = POS[((size_t)b*NTOT + kt*64 + nt*16 + lq)*2];
            const float pos1 = POS[((size_t)b*NTOT + kt*64 + nt*16 + lq)*2 + 1];
            #pragma unroll
            for (int qt = 0; qt < 2; ++qt) {
                f32x4 sa = qcv[qt];   // R17: qcr as C-init (row const matches reg i)
                sa = __builtin_amdgcn_mfma_f32_16x16x32_bf16(aq[qt][0], bx0.v, sa, 0, 0, 0);
                sa = __builtin_amdgcn_mfma_f32_16x16x32_bf16(aq[qt][1], bx1.v, sa, 0, 0, 0);
                #pragma unroll
                for (int i = 0; i < 4; ++i) {
                    float s = sa[i];
                    s = fmaf(qp0r[qt][i], pos0, s);
                    s = fmaf(qp1r[qt][i], pos1, s);
                    const float p = exp2f(s);   // R17: E pre-folded upstream
                    lacc[qt][i] += p;
                    sP[w][qt*16 + quad*4 + i][nt*16 + lq] = (short)f2bf(p);
                }
            }
        }

        {
            unsigned short tmp[16];
            *(uint4*)tmp = t0; *(uint4*)(tmp+8) = t1;
            #pragma unroll
            for (int j = 0; j < 16; ++j) sXc[par][sd0+j][skey] = (short)tmp[j];
        }

        __syncthreads();
    }

    {
        #pragma unroll
        for (int kc = 0; kc < 2; ++kc) {
            U8 pa[2];
            #pragma unroll
            for (int qt = 0; qt < 2; ++qt) {
                const short* pp = &sP[w][qt*16 + lq][kc*32 + quad*8];
                pa[qt].u[0] = *(const unsigned long long*)pp;
                pa[qt].u[1] = *(const unsigned long long*)(pp + 4);
            }
            #pragma unroll
            for (int nt = 0; nt < 4; ++nt) {
                U8 bv;
                const short* xp = &sXc[1][nt*16 + lq][kc*32 + quad*8];
                bv.u[0] = *(const unsigned long long*)xp;
                bv.u[1] = *(const unsigned long long*)(xp + 4);
                O[0][nt] = __builtin_amdgcn_mfma_f32_16x16x32_bf16(pa[0].v, bv.v, O[0][nt], 0, 0, 0);
                O[1][nt] = __builtin_amdgcn_mfma_f32_16x16x32_bf16(pa[1].v, bv.v, O[1][nt], 0, 0, 0);
            }
        }
    }

    // ---- attention epilogue -> sA (bf16) ----
    #pragma unroll
    for (int qt = 0; qt < 2; ++qt)
        #pragma unroll
        for (int i = 0; i < 4; ++i) {
            #pragma unroll
            for (int off = 1; off < 16; off <<= 1)
                lacc[qt][i] += __shfl_xor(lacc[qt][i], off);
            const float rl = 1.f / lacc[qt][i];
            const int row = w*32 + qt*16 + quad*4 + i;
            #pragma unroll
            for (int nt = 0; nt < 4; ++nt)
                sA[row][nt*16 + lq] = (short)f2bf(O[qt][nt][i] * rl);
        }
    if (tid < 64) sw3[tid] = nw3[tid];
    __syncthreads();   // sA complete before head reads (R2 lesson)

    // ---- fused head: 3 MFMA layers (verified k_head body) ----
    const float* Bs[3] = {bvo, nb1, nb2};
    for (int l = 0; l < 3; ++l) {
        bf16x8 wfrag[4][2];
        #pragma unroll
        for (int mt = 0; mt < 4; ++mt)
            #pragma unroll
            for (int kh = 0; kh < 2; ++kh)
                wfrag[mt][kh] = *(const bf16x8*)&WHP[(size_t)(((l*4 + mt)*2 + kh)*64 + lane)*8];
        const float* Bb = Bs[l];
        float be[4][4];
        #pragma unroll
        for (int mt = 0; mt < 4; ++mt)
            #pragma unroll
            for (int i = 0; i < 4; ++i) be[mt][i] = Bb[mt*16 + quad*4 + i];

        short (*src)[68] = (l & 1) ? sB : sA;
        short (*dst)[68] = (l & 1) ? sA : sB;
        const bool doRelu = (l >= 1);

        for (int bt = 0; bt < 2; ++bt) {
            U8 hb0, hb1;
            const short* hp = &src[w*32 + bt*16 + lq][0];
            hb0.u[0] = *(const unsigned long long*)(hp + quad*8);
            hb0.u[1] = *(const unsigned long long*)(hp + quad*8 + 4);
            hb1.u[0] = *(const unsigned long long*)(hp + 32 + quad*8);
            hb1.u[1] = *(const unsigned long long*)(hp + 32 + quad*8 + 4);

            f32x4 acc[4];
            #pragma unroll
            for (int mt = 0; mt < 4; ++mt) acc[mt] = (f32x4){0.f,0.f,0.f,0.f};
            #pragma unroll
            for (int mt = 0; mt < 4; ++mt) {
                acc[mt] = __builtin_amdgcn_mfma_f32_16x16x32_bf16(wfrag[mt][0], hb0.v, acc[mt], 0, 0, 0);
                acc[mt] = __builtin_amdgcn_mfma_f32_16x16x32_bf16(wfrag[mt][1], hb1.v, acc[mt], 0, 0, 0);
            }
            const int row = w*32 + bt*16 + lq;
            #pragma unroll
            for (int mt = 0; mt < 4; ++mt) {
                float v0 = acc[mt][0] + be[mt][0];
                float v1 = acc[mt][1] + be[mt][1];
                float v2 = acc[mt][2] + be[mt][2];
                float v3 = acc[mt][3] + be[mt][3];
                if (doRelu) {
                    v0 = fmaxf(v0, 0.f); v1 = fmaxf(v1, 0.f);
                    v2 = fmaxf(v2, 0.f); v3 = fmaxf(v3, 0.f);
                }
                const unsigned int u0 = (unsigned int)f2bf(v0) | ((unsigned int)f2bf(v1) << 16);
                const unsigned int u1 = (unsigned int)f2bf(v2) | ((unsigned int)f2bf(v3) << 16);
                *(uint2*)&dst[row][mt*16 + quad*4] = make_uint2(u0, u1);
            }
        }
        __syncthreads();
    }

    if (tid < 128) {
        const int row = tid;
        float acc = nb3[0];
        #pragma unroll 16
        for (int d = 0; d < 64; ++d) acc += bf2f(sB[row][d]) * sw3[d];
        OUT[(size_t)b*NPQ + row] = tanhf(acc);
    }
}

// ============================================================================
extern "C" void kernel_launch(void* const* d_in, const int* in_sizes, int n_in,
                              void* d_out, int out_size, void* d_ws, size_t ws_size,
                              hipStream_t stream)
{
    const float* pred = (const float*)d_in[0];
    const float* prey = (const float*)d_in[1];
    const float* obst = (const float*)d_in[2];
    const float* emb  = (const float*)d_in[4];
    const float* e0w1 = (const float*)d_in[5];
    const float* e0b1 = (const float*)d_in[6];
    const float* e0w2 = (const float*)d_in[7];
    const float* e0b2 = (const float*)d_in[8];
    const float* e1w1 = (const float*)d_in[9];
    const float* e1b1 = (const float*)d_in[10];
    const float* e1w2 = (const float*)d_in[11];
    const float* e1b2 = (const float*)d_in[12];
    const float* e2w1 = (const float*)d_in[13];
    const float* e2b1 = (const float*)d_in[14];
    const float* e2w2 = (const float*)d_in[15];
    const float* e2b2 = (const float*)d_in[16];
    const float* wq  = (const float*)d_in[17];
    const float* bq  = (const float*)d_in[18];
    const float* wk  = (const float*)d_in[19];
    const float* bk  = (const float*)d_in[20];
    const float* wvv = (const float*)d_in[21];
    const float* bv  = (const float*)d_in[22];
    const float* wp  = (const float*)d_in[23];
    const float* bp  = (const float*)d_in[24];
    const float* wo  = (const float*)d_in[25];
    const float* bo  = (const float*)d_in[26];
    const float* nw1 = (const float*)d_in[27];
    const float* nb1 = (const float*)d_in[28];
    const float* nw2 = (const float*)d_in[29];
    const float* nb2 = (const float*)d_in[30];
    const float* nw3 = (const float*)d_in[31];
    const float* nb3 = (const float*)d_in[32];

    char* ws = (char*)d_ws;
    unsigned short* X = (unsigned short*)ws;               // 92,274,688 B
    float* F    = (float*)(ws + 92274688);
    float* POS  = F;                  // 1,441,792
    float* QT   = POS + 1441792;      // 4,194,304
    float* QP   = QT  + 4194304;      // 131,072
    float* QC   = QP  + 131072;       // 65,536
    float* a0   = QC  + 65536;        // 64
    float* b0g0 = a0  + 64;           // 4
    float* bvo  = b0g0 + 4;           // 64
    float* BEP  = bvo + 64;           // 192
    float* W2qG = BEP + 192;          // 4,096
    float* WvoG = W2qG + 4096;        // 4,096
    float* scqG = WvoG + 4096;        // 64
    unsigned short* W2P  = (unsigned short*)(scqG + 64);   // 12,288
    unsigned short* AqkP = W2P + 12288;                    // 4,096
    unsigned short* P3P  = AqkP + 4096;                    // 1,024
    unsigned short* WHP  = P3P + 1024;                     // 12,288

    k_prepA<<<43, 256, 0, stream>>>(emb, e0b2, e0w2, wq, bq, wp, bp, bk,
        wvv, bv, wo, bo, e1b2, e1w2, e2b2, e2w2, nw1, nw2,
        W2qG, WvoG, scqG, b0g0, bvo, BEP, W2P, WHP);
    k_prepB<<<4, 256, 0, stream>>>(W2qG, WvoG, scqG, wk, wp, bp, bk,
        AqkP, P3P, a0, WHP);
    k_encq<<<1920, 256, 0, stream>>>(pred, prey, obst, W2P, BEP,
        e0w1, e0b1, e1w1, e1b1, e2w1, e2b1,
        AqkP, a0, P3P, b0g0, X, POS, QT, QP, QC);
    k_attn<<<512, 256, 0, stream>>>(X, POS, QT, QP, QC,
        WHP, bvo, nb1, nb2, nw3, nb3, (float*)d_out);
}